// Round 7
// baseline (579.739 us; speedup 1.0000x reference)
//
#include <hip/hip_runtime.h>
#include <hip/hip_bf16.h>
#include <cstdint>
#include <cstddef>

#define NEG_SLOPE 0.2f

typedef short short8 __attribute__((ext_vector_type(8)));
typedef float f32x4 __attribute__((ext_vector_type(4)));
typedef unsigned short ushort4v __attribute__((ext_vector_type(4)));

__device__ __forceinline__ float lrelu(float x){ return x > 0.f ? x : NEG_SLOPE * x; }
__device__ __forceinline__ float eluf(float x){ return x > 0.f ? x : expm1f(x); }

__device__ __forceinline__ unsigned short f2bf(float f){
  union { float f; unsigned int u; } v; v.f = f;
  unsigned int r = (v.u + 0x7fff + ((v.u >> 16) & 1)) >> 16;  // RNE
  return (unsigned short)r;
}

__device__ __forceinline__ float wave_sum(float v){
#pragma unroll
  for (int d = 32; d > 0; d >>= 1) v += __shfl_xor(v, d, 64);
  return v;
}
__device__ __forceinline__ float wave_max(float v){
#pragma unroll
  for (int d = 32; d > 0; d >>= 1) v = fmaxf(v, __shfl_xor(v, d, 64));
  return v;
}

// ---------------- CSR build ----------------

__global__ __launch_bounds__(256) void k_zero_int(int* p, int n){
  int i = blockIdx.x * 256 + threadIdx.x;
  if (i < n) p[i] = 0;
}

__global__ __launch_bounds__(256) void k_deg(const int* __restrict__ ei, int E, int N,
                                             int* __restrict__ deg){
  int e = blockIdx.x * 256 + threadIdx.x;
  int Et = E + N;
  if (e < Et){
    int d = (e < E) ? ei[E + e] : (e - E);
    atomicAdd(&deg[d], 1);
  }
}

__global__ __launch_bounds__(256) void k_scan_local(const int* __restrict__ deg,
                                                    int* __restrict__ offs,
                                                    int* __restrict__ bsum, int n){
  __shared__ int ws4[4];
  int tid = threadIdx.x, lane = tid & 63, wid = tid >> 6;
  int base = blockIdx.x * 1024 + tid * 4;
  int v[4]; int s = 0;
#pragma unroll
  for (int j = 0; j < 4; j++){ v[j] = (base + j < n) ? deg[base + j] : 0; s += v[j]; }
  int x = s;
#pragma unroll
  for (int d = 1; d < 64; d <<= 1){ int t = __shfl_up(x, d, 64); if (lane >= d) x += t; }
  if (lane == 63) ws4[wid] = x;
  __syncthreads();
  int wbase = 0;
  for (int w = 0; w < wid; w++) wbase += ws4[w];
  int run = wbase + x - s;
#pragma unroll
  for (int j = 0; j < 4; j++){
    if (base + j < n) offs[base + j] = run;
    run += v[j];
  }
  if (tid == 0) bsum[blockIdx.x] = ws4[0] + ws4[1] + ws4[2] + ws4[3];
}

__global__ void k_scan_sums(const int* __restrict__ bsum, int* __restrict__ bbase,
                            int* __restrict__ offs, int n, int nb){
  int lane = threadIdx.x;
  int v = (lane < nb) ? bsum[lane] : 0;
  int x = v;
#pragma unroll
  for (int d = 1; d < 64; d <<= 1){ int t = __shfl_up(x, d, 64); if (lane >= d) x += t; }
  if (lane < nb) bbase[lane] = x - v;
  int total = __shfl(x, nb - 1, 64);
  if (lane == 0) offs[n] = total;
}

__global__ __launch_bounds__(256) void k_scan_add(int* __restrict__ offs,
                                                  const int* __restrict__ bbase, int n){
  int i = blockIdx.x * 256 + threadIdx.x;
  if (i < n) offs[i] += bbase[i >> 10];
}

__global__ __launch_bounds__(256) void k_scatter(const int* __restrict__ ei, int E, int N,
                                                 const int* __restrict__ offs,
                                                 int* __restrict__ cursor,
                                                 int* __restrict__ csr){
  int e = blockIdx.x * 256 + threadIdx.x;
  int Et = E + N;
  if (e < Et){
    int d = (e < E) ? ei[E + e] : (e - E);
    int s = (e < E) ? ei[e]     : (e - E);
    int p = atomicAdd(&cursor[d], 1);
    csr[offs[d] + p] = s;
  }
}

// ---------------- layer 1 ----------------

__global__ __launch_bounds__(256) void k_uvec1(const float* __restrict__ W1,
                                               const float* __restrict__ as1,
                                               const float* __restrict__ ad1,
                                               float* __restrict__ us,
                                               float* __restrict__ ud){
  for (int id = threadIdx.x; id < 528; id += 256){
    int c = id >> 3, h = id & 7;
    const float* wrow = W1 + (size_t)c * 1024 + h * 128;
    float s0 = 0.f, s1 = 0.f;
    for (int m = 0; m < 128; m++){
      float w = wrow[m];
      s0 = fmaf(w, as1[h * 128 + m], s0);
      s1 = fmaf(w, ad1[h * 128 + m], s1);
    }
    us[id] = s0; ud[id] = s1;
  }
}

__global__ __launch_bounds__(256) void k_escore1(const float* __restrict__ x,
                                                 const float* __restrict__ us,
                                                 const float* __restrict__ ud,
                                                 float* __restrict__ ssrc,
                                                 float* __restrict__ sdst, int N){
  int wid = threadIdx.x >> 6, lane = threadIdx.x & 63;
  int n = blockIdx.x * 4 + wid;
  if (n >= N) return;
  float xv0 = x[(size_t)n * 66 + lane];
  int c1 = (lane < 2) ? 64 + lane : 0;
  float xv1 = (lane < 2) ? x[(size_t)n * 66 + c1] : 0.f;
  float es[8], ed[8];
#pragma unroll
  for (int h = 0; h < 8; h++){
    es[h] = xv0 * us[lane * 8 + h] + xv1 * us[c1 * 8 + h];
    ed[h] = xv0 * ud[lane * 8 + h] + xv1 * ud[c1 * 8 + h];
  }
#pragma unroll
  for (int h = 0; h < 8; h++){ es[h] = wave_sum(es[h]); ed[h] = wave_sum(ed[h]); }
  if (lane == 0){
#pragma unroll
    for (int h = 0; h < 8; h++){ ssrc[n * 8 + h] = es[h]; sdst[n * 8 + h] = ed[h]; }
  }
}

// per-node softmax over edges -> normalized alpha[slot][8] (CSR-slot indexed)
__global__ __launch_bounds__(256) void k_alpha1(const int* __restrict__ offs,
                                                const int* __restrict__ csr,
                                                const float* __restrict__ ssrc,
                                                const float* __restrict__ sdst,
                                                float* __restrict__ alp, int N){
  int tid = threadIdx.x, lane = tid & 63, wid = tid >> 6;
  int n = blockIdx.x * 4 + wid;
  if (n >= N) return;
  int o0 = offs[n], o1 = offs[n + 1];
  float sd[8], m[8], z[8];
#pragma unroll
  for (int h = 0; h < 8; h++){ sd[h] = sdst[n * 8 + h]; m[h] = -1e30f; z[h] = 0.f; }

  for (int j = o0 + lane; j < o1; j += 64){
    int s = csr[j];
    const float* sp = ssrc + (size_t)s * 8;
#pragma unroll
    for (int h = 0; h < 8; h++) m[h] = fmaxf(m[h], lrelu(sp[h] + sd[h]));
  }
#pragma unroll
  for (int h = 0; h < 8; h++) m[h] = wave_max(m[h]);

  for (int j = o0 + lane; j < o1; j += 64){
    int s = csr[j];
    const float* sp = ssrc + (size_t)s * 8;
#pragma unroll
    for (int h = 0; h < 8; h++) z[h] += expf(lrelu(sp[h] + sd[h]) - m[h]);
  }
#pragma unroll
  for (int h = 0; h < 8; h++){ z[h] = wave_sum(z[h]); z[h] = 1.f / (z[h] + 1e-16f); }

  for (int j = o0 + lane; j < o1; j += 64){
    int s = csr[j];
    const float* sp = ssrc + (size_t)s * 8;
    float* ap = alp + (size_t)j * 8;
#pragma unroll
    for (int h = 0; h < 8; h++) ap[h] = expf(lrelu(sp[h] + sd[h]) - m[h]) * z[h];
  }
}

// aggregate x: x_agg[n][h][c] = sum_j alp[j][h] * x[src_j][c]; bf16, K padded to 96
__global__ __launch_bounds__(256) void k_agg1(const float* __restrict__ x,
                                              const int* __restrict__ offs,
                                              const int* __restrict__ csr,
                                              const float* __restrict__ alp,
                                              __hip_bfloat16* __restrict__ Xag, int N){
  __shared__ float a_s[4][64][8];
  int tid = threadIdx.x, lane = tid & 63, wid = tid >> 6;
  int n = blockIdx.x * 4 + wid;
  if (n >= N) return;
  int o0 = offs[n], o1 = offs[n + 1];
  float acc[8], acc2[8];
#pragma unroll
  for (int h = 0; h < 8; h++){ acc[h] = 0.f; acc2[h] = 0.f; }
  int c1 = 64 + lane;  // lanes 0,1 only

  for (int cb = o0; cb < o1; cb += 64){
    int cnt = min(64, o1 - cb);
    int sreg = (lane < cnt) ? csr[cb + lane] : 0;
    if (lane < cnt){
      const float4* ap = (const float4*)(alp + (size_t)(cb + lane) * 8);
      *(float4*)&a_s[wid][lane][0] = ap[0];
      *(float4*)&a_s[wid][lane][4] = ap[1];
    }
    for (int jj = 0; jj < cnt; jj++){
      int s = __shfl(sreg, jj, 64);
      float xv = x[(size_t)s * 66 + lane];
      float xv2 = (lane < 2) ? x[(size_t)s * 66 + c1] : 0.f;
      float4 a0 = *(const float4*)&a_s[wid][jj][0];
      float4 a1 = *(const float4*)&a_s[wid][jj][4];
      acc[0] = fmaf(a0.x, xv, acc[0]); acc[1] = fmaf(a0.y, xv, acc[1]);
      acc[2] = fmaf(a0.z, xv, acc[2]); acc[3] = fmaf(a0.w, xv, acc[3]);
      acc[4] = fmaf(a1.x, xv, acc[4]); acc[5] = fmaf(a1.y, xv, acc[5]);
      acc[6] = fmaf(a1.z, xv, acc[6]); acc[7] = fmaf(a1.w, xv, acc[7]);
      if (lane < 2){
        acc2[0] = fmaf(a0.x, xv2, acc2[0]); acc2[1] = fmaf(a0.y, xv2, acc2[1]);
        acc2[2] = fmaf(a0.z, xv2, acc2[2]); acc2[3] = fmaf(a0.w, xv2, acc2[3]);
        acc2[4] = fmaf(a1.x, xv2, acc2[4]); acc2[5] = fmaf(a1.y, xv2, acc2[5]);
        acc2[6] = fmaf(a1.z, xv2, acc2[6]); acc2[7] = fmaf(a1.w, xv2, acc2[7]);
      }
    }
  }

  __hip_bfloat16* base = Xag + (size_t)n * 8 * 96;
#pragma unroll
  for (int h = 0; h < 8; h++) base[h * 96 + lane] = __float2bfloat16(acc[h]);
  if (lane < 32){
    __hip_bfloat16 zero = __float2bfloat16(0.f);
#pragma unroll
    for (int h = 0; h < 8; h++)
      base[h * 96 + 64 + lane] = (lane < 2) ? __float2bfloat16(acc2[h]) : zero;
  }
}

// W1 repack: W1rep[h][col][k] bf16, k in [0,96) zero-padded past 66
__global__ __launch_bounds__(256) void k_w1rep(const float* __restrict__ W1,
                                               __hip_bfloat16* __restrict__ W1rep){
  int id = blockIdx.x * 256 + threadIdx.x;  // 8*128*96 = 98304
  if (id >= 8 * 128 * 96) return;
  int k = id % 96;
  int rc = id / 96;           // h*128 + col
  int col = rc & 127, h = rc >> 7;
  float v = (k < 66) ? W1[(size_t)k * 1024 + h * 128 + col] : 0.f;
  W1rep[id] = __float2bfloat16(v);
}

// layer-1 projection: BARRIER-FREE, no LDS. Fragments loaded global->registers.
// D[m=outcol][n=node]; lane: n = lane&15, k-chunk q = lane>>4.
__global__ __launch_bounds__(256) void k_gemm1_mfma(const __hip_bfloat16* __restrict__ Xag,
                                                    const __hip_bfloat16* __restrict__ W1rep,
                                                    const float* __restrict__ b1,
                                                    __hip_bfloat16* __restrict__ B, int N){
  int tid = threadIdx.x, lane = tid & 63, w = tid >> 6;
  int r0 = blockIdx.x * 128;
  int h  = blockIdx.y;
  int wm = (w >> 1) * 64;   // out-channel base
  int wn = (w & 1) * 64;    // node base
  int n15 = lane & 15, q = lane >> 4;
  f32x4 acc[4][4];
#pragma unroll
  for (int mi = 0; mi < 4; mi++)
#pragma unroll
    for (int ni = 0; ni < 4; ni++) acc[mi][ni] = (f32x4){0.f, 0.f, 0.f, 0.f};

  const short* Xg = (const short*)Xag;
  const short* Wg = (const short*)W1rep;

  int nodes[4];
#pragma unroll
  for (int t = 0; t < 4; t++){
    int nd = r0 + wn + t * 16 + n15;
    nodes[t] = (nd < N) ? nd : (N - 1);
  }

#pragma unroll
  for (int ks = 0; ks < 3; ks++){
    int k0 = ks * 32 + q * 8;
    short8 wf[4], xf[4];
#pragma unroll
    for (int t = 0; t < 4; t++){
      wf[t] = *(const short8*)&Wg[((size_t)h * 128 + wm + t * 16 + n15) * 96 + k0];
      xf[t] = *(const short8*)&Xg[((size_t)nodes[t] * 8 + h) * 96 + k0];
    }
#pragma unroll
    for (int mi = 0; mi < 4; mi++)
#pragma unroll
      for (int ni = 0; ni < 4; ni++)
        acc[mi][ni] = __builtin_amdgcn_mfma_f32_16x16x32_bf16(wf[mi], xf[ni], acc[mi][ni], 0, 0, 0);
  }

#pragma unroll
  for (int mi = 0; mi < 4; mi++){
    int c0 = wm + mi * 16 + q * 4;
    float4 bb = *(const float4*)&b1[h * 128 + c0];
#pragma unroll
    for (int ni = 0; ni < 4; ni++){
      int node = r0 + wn + ni * 16 + n15;
      if (node < N){
        ushort4v o;
        o.x = f2bf(eluf(acc[mi][ni][0] + bb.x));
        o.y = f2bf(eluf(acc[mi][ni][1] + bb.y));
        o.z = f2bf(eluf(acc[mi][ni][2] + bb.z));
        o.w = f2bf(eluf(acc[mi][ni][3] + bb.w));
        *(ushort4v*)((unsigned short*)B + (size_t)node * 1024 + h * 128 + c0) = o;
      }
    }
  }
}

// ---------------- W2 transpose + bf16 ----------------

__global__ __launch_bounds__(256) void k_w2t(const float* __restrict__ W2,
                                             __hip_bfloat16* __restrict__ W2T){
  int id = blockIdx.x * 256 + threadIdx.x;
  int k = id >> 7, n = id & 127;
  W2T[(size_t)n * 1024 + k] = __float2bfloat16(W2[id]);
}

// ---------------- layer 2 GEMM: BARRIER-FREE, no LDS, K=1024 loop ----------------

__global__ __launch_bounds__(256) void k_gemm2_mfma(const __hip_bfloat16* __restrict__ Abf,
                                                    const __hip_bfloat16* __restrict__ W2T,
                                                    float* __restrict__ C, int N){
  int tid = threadIdx.x, lane = tid & 63, w = tid >> 6;
  int r0 = blockIdx.x * 128;
  int wm = (w >> 1) * 64;   // channel base
  int wn = (w & 1) * 64;    // node base
  int n15 = lane & 15, q = lane >> 4;
  f32x4 acc[4][4];
#pragma unroll
  for (int mi = 0; mi < 4; mi++)
#pragma unroll
    for (int ni = 0; ni < 4; ni++) acc[mi][ni] = (f32x4){0.f, 0.f, 0.f, 0.f};

  const short* Ag = (const short*)Abf;
  const short* Wg = (const short*)W2T;

  const short* wbase[4];
  const short* xbase[4];
#pragma unroll
  for (int t = 0; t < 4; t++){
    wbase[t] = Wg + (size_t)(wm + t * 16 + n15) * 1024 + q * 8;
    int nd = r0 + wn + t * 16 + n15;
    if (nd >= N) nd = N - 1;
    xbase[t] = Ag + (size_t)nd * 1024 + q * 8;
  }

#pragma unroll 2
  for (int kt = 0; kt < 1024; kt += 32){
    short8 wf[4], xf[4];
#pragma unroll
    for (int t = 0; t < 4; t++){
      wf[t] = *(const short8*)(wbase[t] + kt);
      xf[t] = *(const short8*)(xbase[t] + kt);
    }
#pragma unroll
    for (int mi = 0; mi < 4; mi++)
#pragma unroll
      for (int ni = 0; ni < 4; ni++)
        acc[mi][ni] = __builtin_amdgcn_mfma_f32_16x16x32_bf16(wf[mi], xf[ni], acc[mi][ni], 0, 0, 0);
  }

#pragma unroll
  for (int mi = 0; mi < 4; mi++){
    int c0 = wm + mi * 16 + q * 4;
#pragma unroll
    for (int ni = 0; ni < 4; ni++){
      int node = r0 + wn + ni * 16 + n15;
      if (node < N) *(f32x4*)&C[(size_t)node * 128 + c0] = acc[mi][ni];
    }
  }
}

// ---------------- narrow GEMM (layer 3): fp32 ----------------

template<int M, int K, int KT>
__global__ __launch_bounds__(256) void k_gemm_n(const float* __restrict__ X,
                                                const float* __restrict__ W,
                                                float* __restrict__ O, int N){
  constexpr int G  = 256 / M;
  constexpr int R  = 16;
  constexpr int RB = G * R;
  __shared__ __align__(16) float xs[RB][KT];
  int tid = threadIdx.x;
  int g = tid / M, col = tid - g * M;
  int r0 = blockIdx.x * RB;
  float acc[R];
#pragma unroll
  for (int r = 0; r < R; r++) acc[r] = 0.f;
  for (int kt = 0; kt < K; kt += KT){
    __syncthreads();
    for (int i = tid; i < RB * KT; i += 256){
      int r = i / KT, k = i - r * KT;
      int row = r0 + r;
      xs[r][k] = (row < N) ? X[(size_t)row * K + kt + k] : 0.f;
    }
    __syncthreads();
    for (int kk = 0; kk < KT; kk += 4){
      float w0 = W[(kt + kk)     * M + col];
      float w1 = W[(kt + kk + 1) * M + col];
      float w2 = W[(kt + kk + 2) * M + col];
      float w3 = W[(kt + kk + 3) * M + col];
#pragma unroll
      for (int r = 0; r < R; r++){
        float4 xv = *(const float4*)&xs[g * R + r][kk];
        acc[r] = fmaf(xv.x, w0, fmaf(xv.y, w1, fmaf(xv.z, w2, fmaf(xv.w, w3, acc[r]))));
      }
    }
  }
  for (int r = 0; r < R; r++){
    int row = r0 + g * R + r;
    if (row < N) O[(size_t)row * M + col] = acc[r];
  }
}

// ---------------- attention dots + aggregation (layers 2,3) ----------------

template<int C>
__global__ __launch_bounds__(256) void k_dots(const float* __restrict__ Hb,
                                              const float* __restrict__ Asrc,
                                              const float* __restrict__ Adst,
                                              float* __restrict__ Ssrc,
                                              float* __restrict__ Sdst, int N){
  int wid = threadIdx.x >> 6, lane = threadIdx.x & 63;
  int n = blockIdx.x * 4 + wid;
  if (n >= N) return;
  const float* hp = Hb + (size_t)n * C;
  float as_ = 0.f, ad_ = 0.f;
#pragma unroll
  for (int c = lane; c < C; c += 64){
    float hv = hp[c];
    as_ += hv * Asrc[c];
    ad_ += hv * Adst[c];
  }
  as_ = wave_sum(as_);
  ad_ = wave_sum(ad_);
  if (lane == 0){ Ssrc[n] = as_; Sdst[n] = ad_; }
}

template<int C, bool FINAL>
__global__ __launch_bounds__(256) void k_agg(const float* __restrict__ Hb,
                                             const int* __restrict__ offs,
                                             const int* __restrict__ csr,
                                             const float* __restrict__ Ssrc,
                                             const float* __restrict__ Sdst,
                                             const float* __restrict__ bias,
                                             const float* __restrict__ Wr,
                                             const float* __restrict__ br,
                                             float* __restrict__ Out, int N){
  int wid = threadIdx.x >> 6, lane = threadIdx.x & 63;
  int n = blockIdx.x * 4 + wid;
  if (n >= N) return;
  int o0 = offs[n], o1 = offs[n + 1];
  float sd = Sdst[n];

  float m = -1e30f;
  for (int j = o0 + lane; j < o1; j += 64){
    int s = csr[j];
    m = fmaxf(m, lrelu(Ssrc[s] + sd));
  }
  m = wave_max(m);

  float z = 0.f;
  for (int j = o0 + lane; j < o1; j += 64){
    int s = csr[j];
    z += expf(lrelu(Ssrc[s] + sd) - m);
  }
  z = wave_sum(z);
  float inv = 1.f / (z + 1e-16f);

  constexpr int CP = C / 64;
  float acc[CP];
#pragma unroll
  for (int r = 0; r < CP; r++) acc[r] = 0.f;

  for (int j = o0; j < o1; j++){
    int s = csr[j];
    float w = expf(lrelu(Ssrc[s] + sd) - m) * inv;
    const float* hp = Hb + (size_t)s * C;
#pragma unroll
    for (int r = 0; r < CP; r++) acc[r] = fmaf(w, hp[lane + r * 64], acc[r]);
  }

  if (!FINAL){
#pragma unroll
    for (int r = 0; r < CP; r++){
      int c = lane + r * 64;
      Out[(size_t)n * C + c] = eluf(acc[r] + bias[c]);
    }
  } else {
    float v = eluf(acc[0] + bias[lane]);
    float t = wave_sum(v * Wr[lane]);
    if (lane == 0) Out[n] = 1.f / (1.f + expf(-(t + br[0])));
  }
}

// ---------------- host launch ----------------

extern "C" void kernel_launch(void* const* d_in, const int* in_sizes, int n_in,
                              void* d_out, int out_size, void* d_ws, size_t ws_size,
                              hipStream_t stream){
  const float* x   = (const float*)d_in[0];
  const int*   ei  = (const int*)  d_in[1];
  const float* W1  = (const float*)d_in[2];
  const float* as1 = (const float*)d_in[3];
  const float* ad1 = (const float*)d_in[4];
  const float* b1  = (const float*)d_in[5];
  const float* W2  = (const float*)d_in[6];
  const float* as2 = (const float*)d_in[7];
  const float* ad2 = (const float*)d_in[8];
  const float* b2  = (const float*)d_in[9];
  const float* W3  = (const float*)d_in[10];
  const float* as3 = (const float*)d_in[11];
  const float* ad3 = (const float*)d_in[12];
  const float* b3  = (const float*)d_in[13];
  const float* Wr  = (const float*)d_in[14];
  const float* br  = (const float*)d_in[15];

  const int N  = in_sizes[0] / 66;
  const int E  = in_sizes[1] / 2;
  const int Et = E + N;
  const int NB = (N + 1023) / 1024;

  size_t off = 0;
  auto take = [&](size_t bytes) -> void* {
    void* p = (char*)d_ws + off;
    off = (off + bytes + 255) & ~(size_t)255;
    return p;
  };
  int*   deg    = (int*)take((size_t)2 * N * 4);
  int*   cursor = deg + N;
  int*   offs   = (int*)take((size_t)(N + 1) * 4);
  int*   csr    = (int*)take((size_t)Et * 4);
  int*   bsum   = (int*)take(64 * 4);
  int*   bbase  = (int*)take(64 * 4);
  float* ssrc   = (float*)take((size_t)N * 8 * 4);
  float* sdst   = (float*)take((size_t)N * 8 * 4);
  float* us     = (float*)take(528 * 4);
  float* ud     = (float*)take(528 * 4);
  __hip_bfloat16* W2T   = (__hip_bfloat16*)take((size_t)128 * 1024 * 2);
  __hip_bfloat16* W1rep = (__hip_bfloat16*)take((size_t)8 * 128 * 96 * 2);
  float* alp    = (float*)take((size_t)Et * 8 * 4);
  // union region: x_agg [N,8,96]bf16 overlays (h2 + out2) [N,128]fp32 x2
  size_t xag_bytes = (size_t)N * 8 * 96 * 2;
  size_t h2o_bytes = (size_t)N * 128 * 4 * 2;
  void*  U = take(xag_bytes > h2o_bytes ? xag_bytes : h2o_bytes);
  __hip_bfloat16* Xag = (__hip_bfloat16*)U;
  float* h2   = (float*)U;
  float* out2 = (float*)((char*)U + (size_t)N * 128 * 4);
  __hip_bfloat16* B = (__hip_bfloat16*)take((size_t)N * 1024 * 2);
  float* h3 = h2;
  (void)ws_size; (void)n_in; (void)out_size;

  // CSR build (graph identical for all layers)
  k_zero_int<<<dim3((2 * N + 255) / 256), dim3(256), 0, stream>>>(deg, 2 * N);
  k_deg<<<dim3((Et + 255) / 256), dim3(256), 0, stream>>>(ei, E, N, deg);
  k_scan_local<<<dim3(NB), dim3(256), 0, stream>>>(deg, offs, bsum, N);
  k_scan_sums<<<dim3(1), dim3(64), 0, stream>>>(bsum, bbase, offs, N, NB);
  k_scan_add<<<dim3((N + 255) / 256), dim3(256), 0, stream>>>(offs, bbase, N);
  k_scatter<<<dim3((Et + 255) / 256), dim3(256), 0, stream>>>(ei, E, N, offs, cursor, csr);

  // layer 1: 66 -> 8x128 concat (alpha precompute, aggregate-x, MFMA project)
  k_uvec1<<<dim3(1), dim3(256), 0, stream>>>(W1, as1, ad1, us, ud);
  k_escore1<<<dim3((N + 3) / 4), dim3(256), 0, stream>>>(x, us, ud, ssrc, sdst, N);
  k_alpha1<<<dim3((N + 3) / 4), dim3(256), 0, stream>>>(offs, csr, ssrc, sdst, alp, N);
  k_agg1<<<dim3((N + 3) / 4), dim3(256), 0, stream>>>(x, offs, csr, alp, Xag, N);
  k_w1rep<<<dim3(384), dim3(256), 0, stream>>>(W1, W1rep);
  k_gemm1_mfma<<<dim3((N + 127) / 128, 8), dim3(256), 0, stream>>>(Xag, W1rep, b1, B, N);

  // layer 2: 1024 -> 128 via bf16 MFMA
  k_w2t<<<dim3(512), dim3(256), 0, stream>>>(W2, W2T);
  k_gemm2_mfma<<<dim3((N + 127) / 128), dim3(256), 0, stream>>>(B, W2T, h2, N);
  k_dots<128><<<dim3((N + 3) / 4), dim3(256), 0, stream>>>(h2, as2, ad2, ssrc, sdst, N);
  k_agg<128, false><<<dim3((N + 3) / 4), dim3(256), 0, stream>>>(
      h2, offs, csr, ssrc, sdst, b2, nullptr, nullptr, out2, N);

  // layer 3: 128 -> 64, fused ELU + Wr + sigmoid
  k_gemm_n<64, 128, 128><<<dim3((N + 63) / 64), dim3(256), 0, stream>>>(out2, W3, h3, N);
  k_dots<64><<<dim3((N + 3) / 4), dim3(256), 0, stream>>>(h3, as3, ad3, ssrc, sdst, N);
  k_agg<64, true><<<dim3((N + 3) / 4), dim3(256), 0, stream>>>(
      h3, offs, csr, ssrc, sdst, b3, Wr, br, (float*)d_out, N);
}

// Round 8
// 527.447 us; speedup vs baseline: 1.0991x; 1.0991x over previous
//
#include <hip/hip_runtime.h>
#include <hip/hip_bf16.h>
#include <cstdint>
#include <cstddef>

#define NEG_SLOPE 0.2f

typedef short short8 __attribute__((ext_vector_type(8)));
typedef float f32x4 __attribute__((ext_vector_type(4)));
typedef unsigned short ushort4v __attribute__((ext_vector_type(4)));

__device__ __forceinline__ float lrelu(float x){ return x > 0.f ? x : NEG_SLOPE * x; }
__device__ __forceinline__ float eluf(float x){ return x > 0.f ? x : expm1f(x); }

__device__ __forceinline__ unsigned short f2bf(float f){
  union { float f; unsigned int u; } v; v.f = f;
  unsigned int r = (v.u + 0x7fff + ((v.u >> 16) & 1)) >> 16;  // RNE
  return (unsigned short)r;
}

__device__ __forceinline__ float wave_sum(float v){
#pragma unroll
  for (int d = 32; d > 0; d >>= 1) v += __shfl_xor(v, d, 64);
  return v;
}
__device__ __forceinline__ float wave_max(float v){
#pragma unroll
  for (int d = 32; d > 0; d >>= 1) v = fmaxf(v, __shfl_xor(v, d, 64));
  return v;
}

// ---------------- CSR build ----------------

__global__ __launch_bounds__(256) void k_zero_int(int* p, int n){
  int i = blockIdx.x * 256 + threadIdx.x;
  if (i < n) p[i] = 0;
}

__global__ __launch_bounds__(256) void k_deg(const int* __restrict__ ei, int E, int N,
                                             int* __restrict__ deg){
  int e = blockIdx.x * 256 + threadIdx.x;
  int Et = E + N;
  if (e < Et){
    int d = (e < E) ? ei[E + e] : (e - E);
    atomicAdd(&deg[d], 1);
  }
}

__global__ __launch_bounds__(256) void k_scan_local(const int* __restrict__ deg,
                                                    int* __restrict__ offs,
                                                    int* __restrict__ bsum, int n){
  __shared__ int ws4[4];
  int tid = threadIdx.x, lane = tid & 63, wid = tid >> 6;
  int base = blockIdx.x * 1024 + tid * 4;
  int v[4]; int s = 0;
#pragma unroll
  for (int j = 0; j < 4; j++){ v[j] = (base + j < n) ? deg[base + j] : 0; s += v[j]; }
  int x = s;
#pragma unroll
  for (int d = 1; d < 64; d <<= 1){ int t = __shfl_up(x, d, 64); if (lane >= d) x += t; }
  if (lane == 63) ws4[wid] = x;
  __syncthreads();
  int wbase = 0;
  for (int w = 0; w < wid; w++) wbase += ws4[w];
  int run = wbase + x - s;
#pragma unroll
  for (int j = 0; j < 4; j++){
    if (base + j < n) offs[base + j] = run;
    run += v[j];
  }
  if (tid == 0) bsum[blockIdx.x] = ws4[0] + ws4[1] + ws4[2] + ws4[3];
}

__global__ void k_scan_sums(const int* __restrict__ bsum, int* __restrict__ bbase,
                            int* __restrict__ offs, int n, int nb){
  int lane = threadIdx.x;
  int v = (lane < nb) ? bsum[lane] : 0;
  int x = v;
#pragma unroll
  for (int d = 1; d < 64; d <<= 1){ int t = __shfl_up(x, d, 64); if (lane >= d) x += t; }
  if (lane < nb) bbase[lane] = x - v;
  int total = __shfl(x, nb - 1, 64);
  if (lane == 0) offs[n] = total;
}

__global__ __launch_bounds__(256) void k_scan_add(int* __restrict__ offs,
                                                  const int* __restrict__ bbase, int n){
  int i = blockIdx.x * 256 + threadIdx.x;
  if (i < n) offs[i] += bbase[i >> 10];
}

__global__ __launch_bounds__(256) void k_scatter(const int* __restrict__ ei, int E, int N,
                                                 const int* __restrict__ offs,
                                                 int* __restrict__ cursor,
                                                 int* __restrict__ csr){
  int e = blockIdx.x * 256 + threadIdx.x;
  int Et = E + N;
  if (e < Et){
    int d = (e < E) ? ei[E + e] : (e - E);
    int s = (e < E) ? ei[e]     : (e - E);
    int p = atomicAdd(&cursor[d], 1);
    csr[offs[d] + p] = s;
  }
}

// ---------------- layer 1 ----------------

__global__ __launch_bounds__(256) void k_uvec1(const float* __restrict__ W1,
                                               const float* __restrict__ as1,
                                               const float* __restrict__ ad1,
                                               float* __restrict__ us,
                                               float* __restrict__ ud){
  for (int id = threadIdx.x; id < 528; id += 256){
    int c = id >> 3, h = id & 7;
    const float* wrow = W1 + (size_t)c * 1024 + h * 128;
    float s0 = 0.f, s1 = 0.f;
    for (int m = 0; m < 128; m++){
      float w = wrow[m];
      s0 = fmaf(w, as1[h * 128 + m], s0);
      s1 = fmaf(w, ad1[h * 128 + m], s1);
    }
    us[id] = s0; ud[id] = s1;
  }
}

__global__ __launch_bounds__(256) void k_escore1(const float* __restrict__ x,
                                                 const float* __restrict__ us,
                                                 const float* __restrict__ ud,
                                                 float* __restrict__ ssrc,
                                                 float* __restrict__ sdst, int N){
  int wid = threadIdx.x >> 6, lane = threadIdx.x & 63;
  int n = blockIdx.x * 4 + wid;
  if (n >= N) return;
  float xv0 = x[(size_t)n * 66 + lane];
  int c1 = (lane < 2) ? 64 + lane : 0;
  float xv1 = (lane < 2) ? x[(size_t)n * 66 + c1] : 0.f;
  float es[8], ed[8];
#pragma unroll
  for (int h = 0; h < 8; h++){
    es[h] = xv0 * us[lane * 8 + h] + xv1 * us[c1 * 8 + h];
    ed[h] = xv0 * ud[lane * 8 + h] + xv1 * ud[c1 * 8 + h];
  }
#pragma unroll
  for (int h = 0; h < 8; h++){ es[h] = wave_sum(es[h]); ed[h] = wave_sum(ed[h]); }
  if (lane == 0){
#pragma unroll
    for (int h = 0; h < 8; h++){ ssrc[n * 8 + h] = es[h]; sdst[n * 8 + h] = ed[h]; }
  }
}

// per-node softmax over edges -> normalized alpha[slot][8] (CSR-slot indexed)
__global__ __launch_bounds__(256) void k_alpha1(const int* __restrict__ offs,
                                                const int* __restrict__ csr,
                                                const float* __restrict__ ssrc,
                                                const float* __restrict__ sdst,
                                                float* __restrict__ alp, int N){
  int tid = threadIdx.x, lane = tid & 63, wid = tid >> 6;
  int n = blockIdx.x * 4 + wid;
  if (n >= N) return;
  int o0 = offs[n], o1 = offs[n + 1];
  float sd[8], m[8], z[8];
#pragma unroll
  for (int h = 0; h < 8; h++){ sd[h] = sdst[n * 8 + h]; m[h] = -1e30f; z[h] = 0.f; }

  for (int j = o0 + lane; j < o1; j += 64){
    int s = csr[j];
    const float* sp = ssrc + (size_t)s * 8;
#pragma unroll
    for (int h = 0; h < 8; h++) m[h] = fmaxf(m[h], lrelu(sp[h] + sd[h]));
  }
#pragma unroll
  for (int h = 0; h < 8; h++) m[h] = wave_max(m[h]);

  for (int j = o0 + lane; j < o1; j += 64){
    int s = csr[j];
    const float* sp = ssrc + (size_t)s * 8;
#pragma unroll
    for (int h = 0; h < 8; h++) z[h] += expf(lrelu(sp[h] + sd[h]) - m[h]);
  }
#pragma unroll
  for (int h = 0; h < 8; h++){ z[h] = wave_sum(z[h]); z[h] = 1.f / (z[h] + 1e-16f); }

  for (int j = o0 + lane; j < o1; j += 64){
    int s = csr[j];
    const float* sp = ssrc + (size_t)s * 8;
    float* ap = alp + (size_t)j * 8;
#pragma unroll
    for (int h = 0; h < 8; h++) ap[h] = expf(lrelu(sp[h] + sd[h]) - m[h]) * z[h];
  }
}

// aggregate x: x_agg[n][h][c] = sum_j alp[j][h] * x[src_j][c]; bf16, K padded to 96
__global__ __launch_bounds__(256) void k_agg1(const float* __restrict__ x,
                                              const int* __restrict__ offs,
                                              const int* __restrict__ csr,
                                              const float* __restrict__ alp,
                                              __hip_bfloat16* __restrict__ Xag, int N){
  __shared__ float a_s[4][64][8];
  int tid = threadIdx.x, lane = tid & 63, wid = tid >> 6;
  int n = blockIdx.x * 4 + wid;
  if (n >= N) return;
  int o0 = offs[n], o1 = offs[n + 1];
  float acc[8], acc2[8];
#pragma unroll
  for (int h = 0; h < 8; h++){ acc[h] = 0.f; acc2[h] = 0.f; }
  int c1 = 64 + lane;  // lanes 0,1 only

  for (int cb = o0; cb < o1; cb += 64){
    int cnt = min(64, o1 - cb);
    int sreg = (lane < cnt) ? csr[cb + lane] : 0;
    if (lane < cnt){
      const float4* ap = (const float4*)(alp + (size_t)(cb + lane) * 8);
      *(float4*)&a_s[wid][lane][0] = ap[0];
      *(float4*)&a_s[wid][lane][4] = ap[1];
    }
    for (int jj = 0; jj < cnt; jj++){
      int s = __shfl(sreg, jj, 64);
      float xv = x[(size_t)s * 66 + lane];
      float xv2 = (lane < 2) ? x[(size_t)s * 66 + c1] : 0.f;
      float4 a0 = *(const float4*)&a_s[wid][jj][0];
      float4 a1 = *(const float4*)&a_s[wid][jj][4];
      acc[0] = fmaf(a0.x, xv, acc[0]); acc[1] = fmaf(a0.y, xv, acc[1]);
      acc[2] = fmaf(a0.z, xv, acc[2]); acc[3] = fmaf(a0.w, xv, acc[3]);
      acc[4] = fmaf(a1.x, xv, acc[4]); acc[5] = fmaf(a1.y, xv, acc[5]);
      acc[6] = fmaf(a1.z, xv, acc[6]); acc[7] = fmaf(a1.w, xv, acc[7]);
      if (lane < 2){
        acc2[0] = fmaf(a0.x, xv2, acc2[0]); acc2[1] = fmaf(a0.y, xv2, acc2[1]);
        acc2[2] = fmaf(a0.z, xv2, acc2[2]); acc2[3] = fmaf(a0.w, xv2, acc2[3]);
        acc2[4] = fmaf(a1.x, xv2, acc2[4]); acc2[5] = fmaf(a1.y, xv2, acc2[5]);
        acc2[6] = fmaf(a1.z, xv2, acc2[6]); acc2[7] = fmaf(a1.w, xv2, acc2[7]);
      }
    }
  }

  __hip_bfloat16* base = Xag + (size_t)n * 8 * 96;
#pragma unroll
  for (int h = 0; h < 8; h++) base[h * 96 + lane] = __float2bfloat16(acc[h]);
  if (lane < 32){
    __hip_bfloat16 zero = __float2bfloat16(0.f);
#pragma unroll
    for (int h = 0; h < 8; h++)
      base[h * 96 + 64 + lane] = (lane < 2) ? __float2bfloat16(acc2[h]) : zero;
  }
}

// W1 repack: W1rep[h][col][k] bf16, k in [0,96) zero-padded past 66
__global__ __launch_bounds__(256) void k_w1rep(const float* __restrict__ W1,
                                               __hip_bfloat16* __restrict__ W1rep){
  int id = blockIdx.x * 256 + threadIdx.x;  // 8*128*96 = 98304
  if (id >= 8 * 128 * 96) return;
  int k = id % 96;
  int rc = id / 96;           // h*128 + col
  int col = rc & 127, h = rc >> 7;
  float v = (k < 66) ? W1[(size_t)k * 1024 + h * 128 + col] : 0.f;
  W1rep[id] = __float2bfloat16(v);
}

// layer-1 projection: barrier-free MFMA (global->reg fragments) +
// LDS-transposed epilogue for fully-coalesced 16B stores.
__global__ __launch_bounds__(256) void k_gemm1_mfma(const __hip_bfloat16* __restrict__ Xag,
                                                    const __hip_bfloat16* __restrict__ W1rep,
                                                    const float* __restrict__ b1,
                                                    __hip_bfloat16* __restrict__ B, int N){
  __shared__ short ob[128 * 136];   // [node][col] pad to 136 shorts (272B, 16B-aligned)
  int tid = threadIdx.x, lane = tid & 63, w = tid >> 6;
  int r0 = blockIdx.x * 128;
  int h  = blockIdx.y;
  int wm = (w >> 1) * 64;   // out-channel base
  int wn = (w & 1) * 64;    // node base
  int n15 = lane & 15, q = lane >> 4;
  f32x4 acc[4][4];
#pragma unroll
  for (int mi = 0; mi < 4; mi++)
#pragma unroll
    for (int ni = 0; ni < 4; ni++) acc[mi][ni] = (f32x4){0.f, 0.f, 0.f, 0.f};

  const short* Xg = (const short*)Xag;
  const short* Wg = (const short*)W1rep;

  int nodes[4];
#pragma unroll
  for (int t = 0; t < 4; t++){
    int nd = r0 + wn + t * 16 + n15;
    nodes[t] = (nd < N) ? nd : (N - 1);
  }

#pragma unroll
  for (int ks = 0; ks < 3; ks++){
    int k0 = ks * 32 + q * 8;
    short8 wf[4], xf[4];
#pragma unroll
    for (int t = 0; t < 4; t++){
      wf[t] = *(const short8*)&Wg[((size_t)h * 128 + wm + t * 16 + n15) * 96 + k0];
      xf[t] = *(const short8*)&Xg[((size_t)nodes[t] * 8 + h) * 96 + k0];
    }
#pragma unroll
    for (int mi = 0; mi < 4; mi++)
#pragma unroll
      for (int ni = 0; ni < 4; ni++)
        acc[mi][ni] = __builtin_amdgcn_mfma_f32_16x16x32_bf16(wf[mi], xf[ni], acc[mi][ni], 0, 0, 0);
  }

  // epilogue part 1: bias + ELU + bf16 -> LDS tile [node][col]
#pragma unroll
  for (int mi = 0; mi < 4; mi++){
    int c0 = wm + mi * 16 + q * 4;
    float4 bb = *(const float4*)&b1[h * 128 + c0];
#pragma unroll
    for (int ni = 0; ni < 4; ni++){
      int nrow = wn + ni * 16 + n15;
      ushort4v o;
      o.x = f2bf(eluf(acc[mi][ni][0] + bb.x));
      o.y = f2bf(eluf(acc[mi][ni][1] + bb.y));
      o.z = f2bf(eluf(acc[mi][ni][2] + bb.z));
      o.w = f2bf(eluf(acc[mi][ni][3] + bb.w));
      *(ushort4v*)&ob[nrow * 136 + c0] = o;
    }
  }
  __syncthreads();

  // epilogue part 2: coalesced streaming write, 16B/lane, full sectors
#pragma unroll
  for (int p = 0; p < 8; p++){
    int c = p * 256 + tid;        // 0..2047 chunks of 16B
    int row = c >> 4, ch = c & 15;
    int node = r0 + row;
    if (node < N){
      short8 v = *(const short8*)&ob[row * 136 + ch * 8];
      *(short8*)((unsigned short*)B + (size_t)node * 1024 + h * 128 + ch * 8) = v;
    }
  }
}

// ---------------- W2 transpose + bf16 ----------------

__global__ __launch_bounds__(256) void k_w2t(const float* __restrict__ W2,
                                             __hip_bfloat16* __restrict__ W2T){
  int id = blockIdx.x * 256 + threadIdx.x;
  int k = id >> 7, n = id & 127;
  W2T[(size_t)n * 1024 + k] = __float2bfloat16(W2[id]);
}

// ---------------- layer 2 GEMM: LDS-staged, operand-swapped ----------------

__global__ __launch_bounds__(256) void k_gemm2_mfma(const __hip_bfloat16* __restrict__ Abf,
                                                    const __hip_bfloat16* __restrict__ W2T,
                                                    float* __restrict__ C, int N){
  __shared__ short As[128 * 32];   // node rows
  __shared__ short Ws[128 * 32];   // channel rows (W2T)
  int tid = threadIdx.x, lane = tid & 63, w = tid >> 6;
  int r0 = blockIdx.x * 128;
  int wm = (w >> 1) * 64;   // channel base
  int wn = (w & 1) * 64;    // node base
  f32x4 acc[4][4];
#pragma unroll
  for (int mi = 0; mi < 4; mi++)
#pragma unroll
    for (int ni = 0; ni < 4; ni++) acc[mi][ni] = (f32x4){0.f, 0.f, 0.f, 0.f};

  const short* Ag = (const short*)Abf;
  const short* Bg = (const short*)W2T;

  for (int kt = 0; kt < 1024; kt += 32){
    __syncthreads();
#pragma unroll
    for (int p = 0; p < 2; p++){
      int i = p * 256 + tid;
      int row = i >> 2, c = i & 3;
      int rg = r0 + row; if (rg > N - 1) rg = N - 1;
      const short* gp = Ag + (size_t)rg * 1024 + kt + c * 8;
      __builtin_amdgcn_global_load_lds((const __attribute__((address_space(1))) void*)gp,
                                       (__attribute__((address_space(3))) void*)&As[i * 8],
                                       16, 0, 0);
      const short* gq = Bg + (size_t)row * 1024 + kt + c * 8;
      __builtin_amdgcn_global_load_lds((const __attribute__((address_space(1))) void*)gq,
                                       (__attribute__((address_space(3))) void*)&Ws[i * 8],
                                       16, 0, 0);
    }
    __syncthreads();
    int ko = (lane >> 4) * 8;
    short8 wf[4], xf[4];
#pragma unroll
    for (int t = 0; t < 4; t++){
      wf[t] = *(const short8*)&Ws[(wm + t * 16 + (lane & 15)) * 32 + ko];
      xf[t] = *(const short8*)&As[(wn + t * 16 + (lane & 15)) * 32 + ko];
    }
#pragma unroll
    for (int mi = 0; mi < 4; mi++)
#pragma unroll
      for (int ni = 0; ni < 4; ni++)
        acc[mi][ni] = __builtin_amdgcn_mfma_f32_16x16x32_bf16(wf[mi], xf[ni], acc[mi][ni], 0, 0, 0);
  }

  int n15 = lane & 15, q = lane >> 4;
#pragma unroll
  for (int mi = 0; mi < 4; mi++){
    int c0 = wm + mi * 16 + q * 4;
#pragma unroll
    for (int ni = 0; ni < 4; ni++){
      int node = r0 + wn + ni * 16 + n15;
      if (node < N) *(f32x4*)&C[(size_t)node * 128 + c0] = acc[mi][ni];
    }
  }
}

// ---------------- narrow GEMM (layer 3): fp32 ----------------

template<int M, int K, int KT>
__global__ __launch_bounds__(256) void k_gemm_n(const float* __restrict__ X,
                                                const float* __restrict__ W,
                                                float* __restrict__ O, int N){
  constexpr int G  = 256 / M;
  constexpr int R  = 16;
  constexpr int RB = G * R;
  __shared__ __align__(16) float xs[RB][KT];
  int tid = threadIdx.x;
  int g = tid / M, col = tid - g * M;
  int r0 = blockIdx.x * RB;
  float acc[R];
#pragma unroll
  for (int r = 0; r < R; r++) acc[r] = 0.f;
  for (int kt = 0; kt < K; kt += KT){
    __syncthreads();
    for (int i = tid; i < RB * KT; i += 256){
      int r = i / KT, k = i - r * KT;
      int row = r0 + r;
      xs[r][k] = (row < N) ? X[(size_t)row * K + kt + k] : 0.f;
    }
    __syncthreads();
    for (int kk = 0; kk < KT; kk += 4){
      float w0 = W[(kt + kk)     * M + col];
      float w1 = W[(kt + kk + 1) * M + col];
      float w2 = W[(kt + kk + 2) * M + col];
      float w3 = W[(kt + kk + 3) * M + col];
#pragma unroll
      for (int r = 0; r < R; r++){
        float4 xv = *(const float4*)&xs[g * R + r][kk];
        acc[r] = fmaf(xv.x, w0, fmaf(xv.y, w1, fmaf(xv.z, w2, fmaf(xv.w, w3, acc[r]))));
      }
    }
  }
  for (int r = 0; r < R; r++){
    int row = r0 + g * R + r;
    if (row < N) O[(size_t)row * M + col] = acc[r];
  }
}

// ---------------- attention dots + aggregation (layers 2,3) ----------------

template<int C>
__global__ __launch_bounds__(256) void k_dots(const float* __restrict__ Hb,
                                              const float* __restrict__ Asrc,
                                              const float* __restrict__ Adst,
                                              float* __restrict__ Ssrc,
                                              float* __restrict__ Sdst, int N){
  int wid = threadIdx.x >> 6, lane = threadIdx.x & 63;
  int n = blockIdx.x * 4 + wid;
  if (n >= N) return;
  const float* hp = Hb + (size_t)n * C;
  float as_ = 0.f, ad_ = 0.f;
#pragma unroll
  for (int c = lane; c < C; c += 64){
    float hv = hp[c];
    as_ += hv * Asrc[c];
    ad_ += hv * Adst[c];
  }
  as_ = wave_sum(as_);
  ad_ = wave_sum(ad_);
  if (lane == 0){ Ssrc[n] = as_; Sdst[n] = ad_; }
}

template<int C, bool FINAL>
__global__ __launch_bounds__(256) void k_agg(const float* __restrict__ Hb,
                                             const int* __restrict__ offs,
                                             const int* __restrict__ csr,
                                             const float* __restrict__ Ssrc,
                                             const float* __restrict__ Sdst,
                                             const float* __restrict__ bias,
                                             const float* __restrict__ Wr,
                                             const float* __restrict__ br,
                                             float* __restrict__ Out, int N){
  int wid = threadIdx.x >> 6, lane = threadIdx.x & 63;
  int n = blockIdx.x * 4 + wid;
  if (n >= N) return;
  int o0 = offs[n], o1 = offs[n + 1];
  float sd = Sdst[n];

  float m = -1e30f;
  for (int j = o0 + lane; j < o1; j += 64){
    int s = csr[j];
    m = fmaxf(m, lrelu(Ssrc[s] + sd));
  }
  m = wave_max(m);

  float z = 0.f;
  for (int j = o0 + lane; j < o1; j += 64){
    int s = csr[j];
    z += expf(lrelu(Ssrc[s] + sd) - m);
  }
  z = wave_sum(z);
  float inv = 1.f / (z + 1e-16f);

  constexpr int CP = C / 64;
  float acc[CP];
#pragma unroll
  for (int r = 0; r < CP; r++) acc[r] = 0.f;

  for (int j = o0; j < o1; j++){
    int s = csr[j];
    float w = expf(lrelu(Ssrc[s] + sd) - m) * inv;
    const float* hp = Hb + (size_t)s * C;
#pragma unroll
    for (int r = 0; r < CP; r++) acc[r] = fmaf(w, hp[lane + r * 64], acc[r]);
  }

  if (!FINAL){
#pragma unroll
    for (int r = 0; r < CP; r++){
      int c = lane + r * 64;
      Out[(size_t)n * C + c] = eluf(acc[r] + bias[c]);
    }
  } else {
    float v = eluf(acc[0] + bias[lane]);
    float t = wave_sum(v * Wr[lane]);
    if (lane == 0) Out[n] = 1.f / (1.f + expf(-(t + br[0])));
  }
}

// ---------------- host launch ----------------

extern "C" void kernel_launch(void* const* d_in, const int* in_sizes, int n_in,
                              void* d_out, int out_size, void* d_ws, size_t ws_size,
                              hipStream_t stream){
  const float* x   = (const float*)d_in[0];
  const int*   ei  = (const int*)  d_in[1];
  const float* W1  = (const float*)d_in[2];
  const float* as1 = (const float*)d_in[3];
  const float* ad1 = (const float*)d_in[4];
  const float* b1  = (const float*)d_in[5];
  const float* W2  = (const float*)d_in[6];
  const float* as2 = (const float*)d_in[7];
  const float* ad2 = (const float*)d_in[8];
  const float* b2  = (const float*)d_in[9];
  const float* W3  = (const float*)d_in[10];
  const float* as3 = (const float*)d_in[11];
  const float* ad3 = (const float*)d_in[12];
  const float* b3  = (const float*)d_in[13];
  const float* Wr  = (const float*)d_in[14];
  const float* br  = (const float*)d_in[15];

  const int N  = in_sizes[0] / 66;
  const int E  = in_sizes[1] / 2;
  const int Et = E + N;
  const int NB = (N + 1023) / 1024;

  size_t off = 0;
  auto take = [&](size_t bytes) -> void* {
    void* p = (char*)d_ws + off;
    off = (off + bytes + 255) & ~(size_t)255;
    return p;
  };
  int*   deg    = (int*)take((size_t)2 * N * 4);
  int*   cursor = deg + N;
  int*   offs   = (int*)take((size_t)(N + 1) * 4);
  int*   csr    = (int*)take((size_t)Et * 4);
  int*   bsum   = (int*)take(64 * 4);
  int*   bbase  = (int*)take(64 * 4);
  float* ssrc   = (float*)take((size_t)N * 8 * 4);
  float* sdst   = (float*)take((size_t)N * 8 * 4);
  float* us     = (float*)take(528 * 4);
  float* ud     = (float*)take(528 * 4);
  __hip_bfloat16* W2T   = (__hip_bfloat16*)take((size_t)128 * 1024 * 2);
  __hip_bfloat16* W1rep = (__hip_bfloat16*)take((size_t)8 * 128 * 96 * 2);
  float* alp    = (float*)take((size_t)Et * 8 * 4);
  // union region: x_agg [N,8,96]bf16 overlays (h2 + out2) [N,128]fp32 x2
  size_t xag_bytes = (size_t)N * 8 * 96 * 2;
  size_t h2o_bytes = (size_t)N * 128 * 4 * 2;
  void*  U = take(xag_bytes > h2o_bytes ? xag_bytes : h2o_bytes);
  __hip_bfloat16* Xag = (__hip_bfloat16*)U;
  float* h2   = (float*)U;
  float* out2 = (float*)((char*)U + (size_t)N * 128 * 4);
  __hip_bfloat16* B = (__hip_bfloat16*)take((size_t)N * 1024 * 2);
  float* h3 = h2;
  (void)ws_size; (void)n_in; (void)out_size;

  // CSR build (graph identical for all layers)
  k_zero_int<<<dim3((2 * N + 255) / 256), dim3(256), 0, stream>>>(deg, 2 * N);
  k_deg<<<dim3((Et + 255) / 256), dim3(256), 0, stream>>>(ei, E, N, deg);
  k_scan_local<<<dim3(NB), dim3(256), 0, stream>>>(deg, offs, bsum, N);
  k_scan_sums<<<dim3(1), dim3(64), 0, stream>>>(bsum, bbase, offs, N, NB);
  k_scan_add<<<dim3((N + 255) / 256), dim3(256), 0, stream>>>(offs, bbase, N);
  k_scatter<<<dim3((Et + 255) / 256), dim3(256), 0, stream>>>(ei, E, N, offs, cursor, csr);

  // layer 1: 66 -> 8x128 concat (alpha precompute, aggregate-x, MFMA project)
  k_uvec1<<<dim3(1), dim3(256), 0, stream>>>(W1, as1, ad1, us, ud);
  k_escore1<<<dim3((N + 3) / 4), dim3(256), 0, stream>>>(x, us, ud, ssrc, sdst, N);
  k_alpha1<<<dim3((N + 3) / 4), dim3(256), 0, stream>>>(offs, csr, ssrc, sdst, alp, N);
  k_agg1<<<dim3((N + 3) / 4), dim3(256), 0, stream>>>(x, offs, csr, alp, Xag, N);
  k_w1rep<<<dim3(384), dim3(256), 0, stream>>>(W1, W1rep);
  k_gemm1_mfma<<<dim3((N + 127) / 128, 8), dim3(256), 0, stream>>>(Xag, W1rep, b1, B, N);

  // layer 2: 1024 -> 128 via bf16 MFMA
  k_w2t<<<dim3(512), dim3(256), 0, stream>>>(W2, W2T);
  k_gemm2_mfma<<<dim3((N + 127) / 128), dim3(256), 0, stream>>>(B, W2T, h2, N);
  k_dots<128><<<dim3((N + 3) / 4), dim3(256), 0, stream>>>(h2, as2, ad2, ssrc, sdst, N);
  k_agg<128, false><<<dim3((N + 3) / 4), dim3(256), 0, stream>>>(
      h2, offs, csr, ssrc, sdst, b2, nullptr, nullptr, out2, N);

  // layer 3: 128 -> 64, fused ELU + Wr + sigmoid
  k_gemm_n<64, 128, 128><<<dim3((N + 63) / 64), dim3(256), 0, stream>>>(out2, W3, h3, N);
  k_dots<64><<<dim3((N + 3) / 4), dim3(256), 0, stream>>>(h3, as3, ad3, ssrc, sdst, N);
  k_agg<64, true><<<dim3((N + 3) / 4), dim3(256), 0, stream>>>(
      h3, offs, csr, ssrc, sdst, b3, Wr, br, (float*)d_out, N);
}

// Round 9
// 517.366 us; speedup vs baseline: 1.1206x; 1.0195x over previous
//
#include <hip/hip_runtime.h>
#include <hip/hip_bf16.h>
#include <cstdint>
#include <cstddef>

#define NEG_SLOPE 0.2f

typedef short short8 __attribute__((ext_vector_type(8)));
typedef float f32x4 __attribute__((ext_vector_type(4)));
typedef unsigned short ushort4v __attribute__((ext_vector_type(4)));

__device__ __forceinline__ float lrelu(float x){ return x > 0.f ? x : NEG_SLOPE * x; }
__device__ __forceinline__ float eluf(float x){ return x > 0.f ? x : expm1f(x); }

__device__ __forceinline__ unsigned short f2bf(float f){
  union { float f; unsigned int u; } v; v.f = f;
  unsigned int r = (v.u + 0x7fff + ((v.u >> 16) & 1)) >> 16;  // RNE
  return (unsigned short)r;
}

// order-preserving float<->uint for atomicMax on signed floats
__device__ __forceinline__ unsigned f2ord(float f){
  unsigned u = __float_as_uint(f);
  return (u >> 31) ? ~u : (u | 0x80000000u);
}
__device__ __forceinline__ float ord2f(unsigned o){
  return (o >> 31) ? __uint_as_float(o & 0x7FFFFFFFu) : __uint_as_float(~o);
}

__device__ __forceinline__ float wave_sum(float v){
#pragma unroll
  for (int d = 32; d > 0; d >>= 1) v += __shfl_xor(v, d, 64);
  return v;
}
__device__ __forceinline__ float wave_max(float v){
#pragma unroll
  for (int d = 32; d > 0; d >>= 1) v = fmaxf(v, __shfl_xor(v, d, 64));
  return v;
}

// ---------------- CSR build ----------------

__global__ __launch_bounds__(256) void k_zero_int(int* p, int n){
  int i = blockIdx.x * 256 + threadIdx.x;
  if (i < n) p[i] = 0;
}

__global__ __launch_bounds__(256) void k_deg(const int* __restrict__ ei, int E, int N,
                                             int* __restrict__ deg){
  int e = blockIdx.x * 256 + threadIdx.x;
  int Et = E + N;
  if (e < Et){
    int d = (e < E) ? ei[E + e] : (e - E);
    atomicAdd(&deg[d], 1);
  }
}

__global__ __launch_bounds__(256) void k_scan_local(const int* __restrict__ deg,
                                                    int* __restrict__ offs,
                                                    int* __restrict__ bsum, int n){
  __shared__ int ws4[4];
  int tid = threadIdx.x, lane = tid & 63, wid = tid >> 6;
  int base = blockIdx.x * 1024 + tid * 4;
  int v[4]; int s = 0;
#pragma unroll
  for (int j = 0; j < 4; j++){ v[j] = (base + j < n) ? deg[base + j] : 0; s += v[j]; }
  int x = s;
#pragma unroll
  for (int d = 1; d < 64; d <<= 1){ int t = __shfl_up(x, d, 64); if (lane >= d) x += t; }
  if (lane == 63) ws4[wid] = x;
  __syncthreads();
  int wbase = 0;
  for (int w = 0; w < wid; w++) wbase += ws4[w];
  int run = wbase + x - s;
#pragma unroll
  for (int j = 0; j < 4; j++){
    if (base + j < n) offs[base + j] = run;
    run += v[j];
  }
  if (tid == 0) bsum[blockIdx.x] = ws4[0] + ws4[1] + ws4[2] + ws4[3];
}

__global__ void k_scan_sums(const int* __restrict__ bsum, int* __restrict__ bbase,
                            int* __restrict__ offs, int n, int nb){
  int lane = threadIdx.x;
  int v = (lane < nb) ? bsum[lane] : 0;
  int x = v;
#pragma unroll
  for (int d = 1; d < 64; d <<= 1){ int t = __shfl_up(x, d, 64); if (lane >= d) x += t; }
  if (lane < nb) bbase[lane] = x - v;
  int total = __shfl(x, nb - 1, 64);
  if (lane == 0) offs[n] = total;
}

__global__ __launch_bounds__(256) void k_scan_add(int* __restrict__ offs,
                                                  const int* __restrict__ bbase, int n){
  int i = blockIdx.x * 256 + threadIdx.x;
  if (i < n) offs[i] += bbase[i >> 10];
}

__global__ __launch_bounds__(256) void k_scatter(const int* __restrict__ ei, int E, int N,
                                                 const int* __restrict__ offs,
                                                 int* __restrict__ cursor,
                                                 int* __restrict__ csr){
  int e = blockIdx.x * 256 + threadIdx.x;
  int Et = E + N;
  if (e < Et){
    int d = (e < E) ? ei[E + e] : (e - E);
    int s = (e < E) ? ei[e]     : (e - E);
    int p = atomicAdd(&cursor[d], 1);
    csr[offs[d] + p] = s;
  }
}

// ---------------- global max reduce (ordered-uint atomic) ----------------

__global__ __launch_bounds__(256) void k_gmax(const float* __restrict__ a,
                                              unsigned* __restrict__ out, int n){
  int i = blockIdx.x * 256 + threadIdx.x;
  int stride = gridDim.x * 256;
  float m = -1e30f;
  for (; i < n; i += stride) m = fmaxf(m, a[i]);
  m = wave_max(m);
  if ((threadIdx.x & 63) == 0) atomicMax(out, f2ord(m));
}

// ---------------- layer 1 ----------------

__global__ __launch_bounds__(256) void k_uvec1(const float* __restrict__ W1,
                                               const float* __restrict__ as1,
                                               const float* __restrict__ ad1,
                                               float* __restrict__ us,
                                               float* __restrict__ ud){
  for (int id = threadIdx.x; id < 528; id += 256){
    int c = id >> 3, h = id & 7;
    const float* wrow = W1 + (size_t)c * 1024 + h * 128;
    float s0 = 0.f, s1 = 0.f;
    for (int m = 0; m < 128; m++){
      float w = wrow[m];
      s0 = fmaf(w, as1[h * 128 + m], s0);
      s1 = fmaf(w, ad1[h * 128 + m], s1);
    }
    us[id] = s0; ud[id] = s1;
  }
}

__global__ __launch_bounds__(256) void k_escore1(const float* __restrict__ x,
                                                 const float* __restrict__ us,
                                                 const float* __restrict__ ud,
                                                 float* __restrict__ ssrc,
                                                 float* __restrict__ sdst, int N){
  int wid = threadIdx.x >> 6, lane = threadIdx.x & 63;
  int n = blockIdx.x * 4 + wid;
  if (n >= N) return;
  float xv0 = x[(size_t)n * 66 + lane];
  int c1 = (lane < 2) ? 64 + lane : 0;
  float xv1 = (lane < 2) ? x[(size_t)n * 66 + c1] : 0.f;
  float es[8], ed[8];
#pragma unroll
  for (int h = 0; h < 8; h++){
    es[h] = xv0 * us[lane * 8 + h] + xv1 * us[c1 * 8 + h];
    ed[h] = xv0 * ud[lane * 8 + h] + xv1 * ud[c1 * 8 + h];
  }
#pragma unroll
  for (int h = 0; h < 8; h++){ es[h] = wave_sum(es[h]); ed[h] = wave_sum(ed[h]); }
  if (lane == 0){
#pragma unroll
    for (int h = 0; h < 8; h++){ ssrc[n * 8 + h] = es[h]; sdst[n * 8 + h] = ed[h]; }
  }
}

// one node per THREAD: single gather pass; unnormalized w -> alp, zinv per (node,head)
__global__ __launch_bounds__(256) void k_alpha1(const int* __restrict__ offs,
                                                const int* __restrict__ csr,
                                                const float* __restrict__ ssrc,
                                                const float* __restrict__ sdst,
                                                const unsigned* __restrict__ gm,
                                                float* __restrict__ alp,
                                                float* __restrict__ zinv, int N){
  int n = blockIdx.x * 256 + threadIdx.x;
  if (n >= N) return;
  float M = lrelu(ord2f(gm[0]) + ord2f(gm[1]));
  float4 sd0 = *(const float4*)&sdst[(size_t)n * 8];
  float4 sd1 = *(const float4*)&sdst[(size_t)n * 8 + 4];
  float z[8];
#pragma unroll
  for (int h = 0; h < 8; h++) z[h] = 0.f;
  int o0 = offs[n], o1 = offs[n + 1];
  for (int j = o0; j < o1; j++){
    int s = csr[j];
    float4 a0 = *(const float4*)&ssrc[(size_t)s * 8];
    float4 a1 = *(const float4*)&ssrc[(size_t)s * 8 + 4];
    float4 w0, w1;
    w0.x = __expf(lrelu(a0.x + sd0.x) - M);
    w0.y = __expf(lrelu(a0.y + sd0.y) - M);
    w0.z = __expf(lrelu(a0.z + sd0.z) - M);
    w0.w = __expf(lrelu(a0.w + sd0.w) - M);
    w1.x = __expf(lrelu(a1.x + sd1.x) - M);
    w1.y = __expf(lrelu(a1.y + sd1.y) - M);
    w1.z = __expf(lrelu(a1.z + sd1.z) - M);
    w1.w = __expf(lrelu(a1.w + sd1.w) - M);
    z[0] += w0.x; z[1] += w0.y; z[2] += w0.z; z[3] += w0.w;
    z[4] += w1.x; z[5] += w1.y; z[6] += w1.z; z[7] += w1.w;
    *(float4*)&alp[(size_t)j * 8]     = w0;
    *(float4*)&alp[(size_t)j * 8 + 4] = w1;
  }
  float4 zi0, zi1;
  zi0.x = 1.f / (z[0] + 1e-16f); zi0.y = 1.f / (z[1] + 1e-16f);
  zi0.z = 1.f / (z[2] + 1e-16f); zi0.w = 1.f / (z[3] + 1e-16f);
  zi1.x = 1.f / (z[4] + 1e-16f); zi1.y = 1.f / (z[5] + 1e-16f);
  zi1.z = 1.f / (z[6] + 1e-16f); zi1.w = 1.f / (z[7] + 1e-16f);
  *(float4*)&zinv[(size_t)n * 8]     = zi0;
  *(float4*)&zinv[(size_t)n * 8 + 4] = zi1;
}

// aggregate x with UNNORMALIZED w, scale by zinv at end; bf16 out, K padded to 96
__global__ __launch_bounds__(256) void k_agg1(const float* __restrict__ x,
                                              const int* __restrict__ offs,
                                              const int* __restrict__ csr,
                                              const float* __restrict__ alp,
                                              const float* __restrict__ zinv,
                                              __hip_bfloat16* __restrict__ Xag, int N){
  __shared__ float a_s[4][64][8];
  int tid = threadIdx.x, lane = tid & 63, wid = tid >> 6;
  int n = blockIdx.x * 4 + wid;
  if (n >= N) return;
  int o0 = offs[n], o1 = offs[n + 1];
  float acc[8], acc2[8];
#pragma unroll
  for (int h = 0; h < 8; h++){ acc[h] = 0.f; acc2[h] = 0.f; }
  int c1 = 64 + lane;  // lanes 0,1 only

  for (int cb = o0; cb < o1; cb += 64){
    int cnt = min(64, o1 - cb);
    int sreg = (lane < cnt) ? csr[cb + lane] : 0;
    if (lane < cnt){
      const float4* ap = (const float4*)(alp + (size_t)(cb + lane) * 8);
      *(float4*)&a_s[wid][lane][0] = ap[0];
      *(float4*)&a_s[wid][lane][4] = ap[1];
    }
    for (int jj = 0; jj < cnt; jj++){
      int s = __shfl(sreg, jj, 64);
      float xv = x[(size_t)s * 66 + lane];
      float xv2 = (lane < 2) ? x[(size_t)s * 66 + c1] : 0.f;
      float4 a0 = *(const float4*)&a_s[wid][jj][0];
      float4 a1 = *(const float4*)&a_s[wid][jj][4];
      acc[0] = fmaf(a0.x, xv, acc[0]); acc[1] = fmaf(a0.y, xv, acc[1]);
      acc[2] = fmaf(a0.z, xv, acc[2]); acc[3] = fmaf(a0.w, xv, acc[3]);
      acc[4] = fmaf(a1.x, xv, acc[4]); acc[5] = fmaf(a1.y, xv, acc[5]);
      acc[6] = fmaf(a1.z, xv, acc[6]); acc[7] = fmaf(a1.w, xv, acc[7]);
      if (lane < 2){
        acc2[0] = fmaf(a0.x, xv2, acc2[0]); acc2[1] = fmaf(a0.y, xv2, acc2[1]);
        acc2[2] = fmaf(a0.z, xv2, acc2[2]); acc2[3] = fmaf(a0.w, xv2, acc2[3]);
        acc2[4] = fmaf(a1.x, xv2, acc2[4]); acc2[5] = fmaf(a1.y, xv2, acc2[5]);
        acc2[6] = fmaf(a1.z, xv2, acc2[6]); acc2[7] = fmaf(a1.w, xv2, acc2[7]);
      }
    }
  }

  float zi[8];
#pragma unroll
  for (int h = 0; h < 8; h++) zi[h] = zinv[(size_t)n * 8 + h];

  __hip_bfloat16* base = Xag + (size_t)n * 8 * 96;
#pragma unroll
  for (int h = 0; h < 8; h++) base[h * 96 + lane] = __float2bfloat16(acc[h] * zi[h]);
  if (lane < 32){
    __hip_bfloat16 zero = __float2bfloat16(0.f);
#pragma unroll
    for (int h = 0; h < 8; h++)
      base[h * 96 + 64 + lane] = (lane < 2) ? __float2bfloat16(acc2[h] * zi[h]) : zero;
  }
}

// W1 repack: W1rep[h][col][k] bf16, k in [0,96) zero-padded past 66
__global__ __launch_bounds__(256) void k_w1rep(const float* __restrict__ W1,
                                               __hip_bfloat16* __restrict__ W1rep){
  int id = blockIdx.x * 256 + threadIdx.x;
  if (id >= 8 * 128 * 96) return;
  int k = id % 96;
  int rc = id / 96;
  int col = rc & 127, h = rc >> 7;
  float v = (k < 66) ? W1[(size_t)k * 1024 + h * 128 + col] : 0.f;
  W1rep[id] = __float2bfloat16(v);
}

// layer-1 projection: barrier-free MFMA + LDS-transposed epilogue (coalesced stores)
__global__ __launch_bounds__(256) void k_gemm1_mfma(const __hip_bfloat16* __restrict__ Xag,
                                                    const __hip_bfloat16* __restrict__ W1rep,
                                                    const float* __restrict__ b1,
                                                    __hip_bfloat16* __restrict__ B, int N){
  __shared__ short ob[128 * 136];
  int tid = threadIdx.x, lane = tid & 63, w = tid >> 6;
  int r0 = blockIdx.x * 128;
  int h  = blockIdx.y;
  int wm = (w >> 1) * 64;
  int wn = (w & 1) * 64;
  int n15 = lane & 15, q = lane >> 4;
  f32x4 acc[4][4];
#pragma unroll
  for (int mi = 0; mi < 4; mi++)
#pragma unroll
    for (int ni = 0; ni < 4; ni++) acc[mi][ni] = (f32x4){0.f, 0.f, 0.f, 0.f};

  const short* Xg = (const short*)Xag;
  const short* Wg = (const short*)W1rep;

  int nodes[4];
#pragma unroll
  for (int t = 0; t < 4; t++){
    int nd = r0 + wn + t * 16 + n15;
    nodes[t] = (nd < N) ? nd : (N - 1);
  }

#pragma unroll
  for (int ks = 0; ks < 3; ks++){
    int k0 = ks * 32 + q * 8;
    short8 wf[4], xf[4];
#pragma unroll
    for (int t = 0; t < 4; t++){
      wf[t] = *(const short8*)&Wg[((size_t)h * 128 + wm + t * 16 + n15) * 96 + k0];
      xf[t] = *(const short8*)&Xg[((size_t)nodes[t] * 8 + h) * 96 + k0];
    }
#pragma unroll
    for (int mi = 0; mi < 4; mi++)
#pragma unroll
      for (int ni = 0; ni < 4; ni++)
        acc[mi][ni] = __builtin_amdgcn_mfma_f32_16x16x32_bf16(wf[mi], xf[ni], acc[mi][ni], 0, 0, 0);
  }

#pragma unroll
  for (int mi = 0; mi < 4; mi++){
    int c0 = wm + mi * 16 + q * 4;
    float4 bb = *(const float4*)&b1[h * 128 + c0];
#pragma unroll
    for (int ni = 0; ni < 4; ni++){
      int nrow = wn + ni * 16 + n15;
      ushort4v o;
      o.x = f2bf(eluf(acc[mi][ni][0] + bb.x));
      o.y = f2bf(eluf(acc[mi][ni][1] + bb.y));
      o.z = f2bf(eluf(acc[mi][ni][2] + bb.z));
      o.w = f2bf(eluf(acc[mi][ni][3] + bb.w));
      *(ushort4v*)&ob[nrow * 136 + c0] = o;
    }
  }
  __syncthreads();

#pragma unroll
  for (int p = 0; p < 8; p++){
    int c = p * 256 + tid;
    int row = c >> 4, ch = c & 15;
    int node = r0 + row;
    if (node < N){
      short8 v = *(const short8*)&ob[row * 136 + ch * 8];
      *(short8*)((unsigned short*)B + (size_t)node * 1024 + h * 128 + ch * 8) = v;
    }
  }
}

// ---------------- W2 transpose + bf16 ----------------

__global__ __launch_bounds__(256) void k_w2t(const float* __restrict__ W2,
                                             __hip_bfloat16* __restrict__ W2T){
  int id = blockIdx.x * 256 + threadIdx.x;
  int k = id >> 7, n = id & 127;
  W2T[(size_t)n * 1024 + k] = __float2bfloat16(W2[id]);
}

// ---------------- layer 2 GEMM: LDS-staged, operand-swapped ----------------

__global__ __launch_bounds__(256) void k_gemm2_mfma(const __hip_bfloat16* __restrict__ Abf,
                                                    const __hip_bfloat16* __restrict__ W2T,
                                                    float* __restrict__ C, int N){
  __shared__ short As[128 * 32];
  __shared__ short Ws[128 * 32];
  int tid = threadIdx.x, lane = tid & 63, w = tid >> 6;
  int r0 = blockIdx.x * 128;
  int wm = (w >> 1) * 64;
  int wn = (w & 1) * 64;
  f32x4 acc[4][4];
#pragma unroll
  for (int mi = 0; mi < 4; mi++)
#pragma unroll
    for (int ni = 0; ni < 4; ni++) acc[mi][ni] = (f32x4){0.f, 0.f, 0.f, 0.f};

  const short* Ag = (const short*)Abf;
  const short* Bg = (const short*)W2T;

  for (int kt = 0; kt < 1024; kt += 32){
    __syncthreads();
#pragma unroll
    for (int p = 0; p < 2; p++){
      int i = p * 256 + tid;
      int row = i >> 2, c = i & 3;
      int rg = r0 + row; if (rg > N - 1) rg = N - 1;
      const short* gp = Ag + (size_t)rg * 1024 + kt + c * 8;
      __builtin_amdgcn_global_load_lds((const __attribute__((address_space(1))) void*)gp,
                                       (__attribute__((address_space(3))) void*)&As[i * 8],
                                       16, 0, 0);
      const short* gq = Bg + (size_t)row * 1024 + kt + c * 8;
      __builtin_amdgcn_global_load_lds((const __attribute__((address_space(1))) void*)gq,
                                       (__attribute__((address_space(3))) void*)&Ws[i * 8],
                                       16, 0, 0);
    }
    __syncthreads();
    int ko = (lane >> 4) * 8;
    short8 wf[4], xf[4];
#pragma unroll
    for (int t = 0; t < 4; t++){
      wf[t] = *(const short8*)&Ws[(wm + t * 16 + (lane & 15)) * 32 + ko];
      xf[t] = *(const short8*)&As[(wn + t * 16 + (lane & 15)) * 32 + ko];
    }
#pragma unroll
    for (int mi = 0; mi < 4; mi++)
#pragma unroll
      for (int ni = 0; ni < 4; ni++)
        acc[mi][ni] = __builtin_amdgcn_mfma_f32_16x16x32_bf16(wf[mi], xf[ni], acc[mi][ni], 0, 0, 0);
  }

  int n15 = lane & 15, q = lane >> 4;
#pragma unroll
  for (int mi = 0; mi < 4; mi++){
    int c0 = wm + mi * 16 + q * 4;
#pragma unroll
    for (int ni = 0; ni < 4; ni++){
      int node = r0 + wn + ni * 16 + n15;
      if (node < N) *(f32x4*)&C[(size_t)node * 128 + c0] = acc[mi][ni];
    }
  }
}

// ---------------- narrow GEMM (layer 3): fp32 ----------------

template<int M, int K, int KT>
__global__ __launch_bounds__(256) void k_gemm_n(const float* __restrict__ X,
                                                const float* __restrict__ W,
                                                float* __restrict__ O, int N){
  constexpr int G  = 256 / M;
  constexpr int R  = 16;
  constexpr int RB = G * R;
  __shared__ __align__(16) float xs[RB][KT];
  int tid = threadIdx.x;
  int g = tid / M, col = tid - g * M;
  int r0 = blockIdx.x * RB;
  float acc[R];
#pragma unroll
  for (int r = 0; r < R; r++) acc[r] = 0.f;
  for (int kt = 0; kt < K; kt += KT){
    __syncthreads();
    for (int i = tid; i < RB * KT; i += 256){
      int r = i / KT, k = i - r * KT;
      int row = r0 + r;
      xs[r][k] = (row < N) ? X[(size_t)row * K + kt + k] : 0.f;
    }
    __syncthreads();
    for (int kk = 0; kk < KT; kk += 4){
      float w0 = W[(kt + kk)     * M + col];
      float w1 = W[(kt + kk + 1) * M + col];
      float w2 = W[(kt + kk + 2) * M + col];
      float w3 = W[(kt + kk + 3) * M + col];
#pragma unroll
      for (int r = 0; r < R; r++){
        float4 xv = *(const float4*)&xs[g * R + r][kk];
        acc[r] = fmaf(xv.x, w0, fmaf(xv.y, w1, fmaf(xv.z, w2, fmaf(xv.w, w3, acc[r]))));
      }
    }
  }
  for (int r = 0; r < R; r++){
    int row = r0 + g * R + r;
    if (row < N) O[(size_t)row * M + col] = acc[r];
  }
}

// ---------------- attention dots + z + aggregation (layers 2,3) ----------------

template<int C>
__global__ __launch_bounds__(256) void k_dots(const float* __restrict__ Hb,
                                              const float* __restrict__ Asrc,
                                              const float* __restrict__ Adst,
                                              float* __restrict__ Ssrc,
                                              float* __restrict__ Sdst, int N){
  int wid = threadIdx.x >> 6, lane = threadIdx.x & 63;
  int n = blockIdx.x * 4 + wid;
  if (n >= N) return;
  const float* hp = Hb + (size_t)n * C;
  float as_ = 0.f, ad_ = 0.f;
#pragma unroll
  for (int c = lane; c < C; c += 64){
    float hv = hp[c];
    as_ += hv * Asrc[c];
    ad_ += hv * Adst[c];
  }
  as_ = wave_sum(as_);
  ad_ = wave_sum(ad_);
  if (lane == 0){ Ssrc[n] = as_; Sdst[n] = ad_; }
}

// one node per thread: z = sum_j exp(lrelu(es+ed)-M) -> zinv
__global__ __launch_bounds__(256) void k_zed(const int* __restrict__ offs,
                                             const int* __restrict__ csr,
                                             const float* __restrict__ Ssrc,
                                             const float* __restrict__ Sdst,
                                             const unsigned* __restrict__ gm,
                                             float* __restrict__ zinv, int N){
  int n = blockIdx.x * 256 + threadIdx.x;
  if (n >= N) return;
  float M = lrelu(ord2f(gm[0]) + ord2f(gm[1]));
  float sd = Sdst[n];
  float z = 0.f;
  int o0 = offs[n], o1 = offs[n + 1];
  for (int j = o0; j < o1; j++)
    z += __expf(lrelu(Ssrc[csr[j]] + sd) - M);
  zinv[n] = 1.f / (z + 1e-16f);
}

template<int C, bool FINAL>
__global__ __launch_bounds__(256) void k_agg(const float* __restrict__ Hb,
                                             const int* __restrict__ offs,
                                             const int* __restrict__ csr,
                                             const float* __restrict__ Ssrc,
                                             const float* __restrict__ Sdst,
                                             const unsigned* __restrict__ gm,
                                             const float* __restrict__ zinv,
                                             const float* __restrict__ bias,
                                             const float* __restrict__ Wr,
                                             const float* __restrict__ br,
                                             float* __restrict__ Out, int N){
  int wid = threadIdx.x >> 6, lane = threadIdx.x & 63;
  int n = blockIdx.x * 4 + wid;
  if (n >= N) return;
  int o0 = offs[n], o1 = offs[n + 1];
  float M = lrelu(ord2f(gm[0]) + ord2f(gm[1]));
  float sd = Sdst[n];
  float iz = zinv[n];

  constexpr int CP = C / 64;
  float acc[CP];
#pragma unroll
  for (int r = 0; r < CP; r++) acc[r] = 0.f;

  for (int j = o0; j < o1; j++){
    int s = csr[j];
    float w = __expf(lrelu(Ssrc[s] + sd) - M);
    const float* hp = Hb + (size_t)s * C;
#pragma unroll
    for (int r = 0; r < CP; r++) acc[r] = fmaf(w, hp[lane + r * 64], acc[r]);
  }

  if (!FINAL){
#pragma unroll
    for (int r = 0; r < CP; r++){
      int c = lane + r * 64;
      Out[(size_t)n * C + c] = eluf(acc[r] * iz + bias[c]);
    }
  } else {
    float v = eluf(acc[0] * iz + bias[lane]);
    float t = wave_sum(v * Wr[lane]);
    if (lane == 0) Out[n] = 1.f / (1.f + expf(-(t + br[0])));
  }
}

// ---------------- host launch ----------------

extern "C" void kernel_launch(void* const* d_in, const int* in_sizes, int n_in,
                              void* d_out, int out_size, void* d_ws, size_t ws_size,
                              hipStream_t stream){
  const float* x   = (const float*)d_in[0];
  const int*   ei  = (const int*)  d_in[1];
  const float* W1  = (const float*)d_in[2];
  const float* as1 = (const float*)d_in[3];
  const float* ad1 = (const float*)d_in[4];
  const float* b1  = (const float*)d_in[5];
  const float* W2  = (const float*)d_in[6];
  const float* as2 = (const float*)d_in[7];
  const float* ad2 = (const float*)d_in[8];
  const float* b2  = (const float*)d_in[9];
  const float* W3  = (const float*)d_in[10];
  const float* as3 = (const float*)d_in[11];
  const float* ad3 = (const float*)d_in[12];
  const float* b3  = (const float*)d_in[13];
  const float* Wr  = (const float*)d_in[14];
  const float* br  = (const float*)d_in[15];

  const int N  = in_sizes[0] / 66;
  const int E  = in_sizes[1] / 2;
  const int Et = E + N;
  const int NB = (N + 1023) / 1024;
  const int NT = (N + 255) / 256;

  size_t off = 0;
  auto take = [&](size_t bytes) -> void* {
    void* p = (char*)d_ws + off;
    off = (off + bytes + 255) & ~(size_t)255;
    return p;
  };
  int*   deg    = (int*)take((size_t)2 * N * 4);
  int*   cursor = deg + N;
  int*   offs   = (int*)take((size_t)(N + 1) * 4);
  int*   csr    = (int*)take((size_t)Et * 4);
  int*   bsum   = (int*)take(64 * 4);
  int*   bbase  = (int*)take(64 * 4);
  unsigned* gm  = (unsigned*)take(8 * 4);
  float* ssrc   = (float*)take((size_t)N * 8 * 4);
  float* sdst   = (float*)take((size_t)N * 8 * 4);
  float* zi     = (float*)take((size_t)N * 8 * 4);
  float* us     = (float*)take(528 * 4);
  float* ud     = (float*)take(528 * 4);
  __hip_bfloat16* W2T   = (__hip_bfloat16*)take((size_t)128 * 1024 * 2);
  __hip_bfloat16* W1rep = (__hip_bfloat16*)take((size_t)8 * 128 * 96 * 2);
  float* alp    = (float*)take((size_t)Et * 8 * 4);
  size_t xag_bytes = (size_t)N * 8 * 96 * 2;
  size_t h2o_bytes = (size_t)N * 128 * 4 * 2;
  void*  U = take(xag_bytes > h2o_bytes ? xag_bytes : h2o_bytes);
  __hip_bfloat16* Xag = (__hip_bfloat16*)U;
  float* h2   = (float*)U;
  float* out2 = (float*)((char*)U + (size_t)N * 128 * 4);
  __hip_bfloat16* B = (__hip_bfloat16*)take((size_t)N * 1024 * 2);
  float* h3 = h2;
  (void)ws_size; (void)n_in; (void)out_size;

  // CSR build + init
  k_zero_int<<<dim3((2 * N + 255) / 256), dim3(256), 0, stream>>>(deg, 2 * N);
  k_zero_int<<<dim3(1), dim3(256), 0, stream>>>((int*)gm, 8);
  k_deg<<<dim3((Et + 255) / 256), dim3(256), 0, stream>>>(ei, E, N, deg);
  k_scan_local<<<dim3(NB), dim3(256), 0, stream>>>(deg, offs, bsum, N);
  k_scan_sums<<<dim3(1), dim3(64), 0, stream>>>(bsum, bbase, offs, N, NB);
  k_scan_add<<<dim3((N + 255) / 256), dim3(256), 0, stream>>>(offs, bbase, N);
  k_scatter<<<dim3((Et + 255) / 256), dim3(256), 0, stream>>>(ei, E, N, offs, cursor, csr);

  // layer 1
  k_uvec1<<<dim3(1), dim3(256), 0, stream>>>(W1, as1, ad1, us, ud);
  k_escore1<<<dim3((N + 3) / 4), dim3(256), 0, stream>>>(x, us, ud, ssrc, sdst, N);
  k_gmax<<<dim3(128), dim3(256), 0, stream>>>(ssrc, &gm[0], N * 8);
  k_gmax<<<dim3(128), dim3(256), 0, stream>>>(sdst, &gm[1], N * 8);
  k_alpha1<<<dim3(NT), dim3(256), 0, stream>>>(offs, csr, ssrc, sdst, gm, alp, zi, N);
  k_agg1<<<dim3((N + 3) / 4), dim3(256), 0, stream>>>(x, offs, csr, alp, zi, Xag, N);
  k_w1rep<<<dim3(384), dim3(256), 0, stream>>>(W1, W1rep);
  k_gemm1_mfma<<<dim3((N + 127) / 128, 8), dim3(256), 0, stream>>>(Xag, W1rep, b1, B, N);

  // layer 2
  k_w2t<<<dim3(512), dim3(256), 0, stream>>>(W2, W2T);
  k_gemm2_mfma<<<dim3((N + 127) / 128), dim3(256), 0, stream>>>(B, W2T, h2, N);
  k_dots<128><<<dim3((N + 3) / 4), dim3(256), 0, stream>>>(h2, as2, ad2, ssrc, sdst, N);
  k_gmax<<<dim3(128), dim3(256), 0, stream>>>(ssrc, &gm[2], N);
  k_gmax<<<dim3(128), dim3(256), 0, stream>>>(sdst, &gm[3], N);
  k_zed<<<dim3(NT), dim3(256), 0, stream>>>(offs, csr, ssrc, sdst, &gm[2], zi, N);
  k_agg<128, false><<<dim3((N + 3) / 4), dim3(256), 0, stream>>>(
      h2, offs, csr, ssrc, sdst, &gm[2], zi, b2, nullptr, nullptr, out2, N);

  // layer 3
  k_gemm_n<64, 128, 128><<<dim3((N + 63) / 64), dim3(256), 0, stream>>>(out2, W3, h3, N);
  k_dots<64><<<dim3((N + 3) / 4), dim3(256), 0, stream>>>(h3, as3, ad3, ssrc, sdst, N);
  k_gmax<<<dim3(128), dim3(256), 0, stream>>>(ssrc, &gm[4], N);
  k_gmax<<<dim3(128), dim3(256), 0, stream>>>(sdst, &gm[5], N);
  k_zed<<<dim3(NT), dim3(256), 0, stream>>>(offs, csr, ssrc, sdst, &gm[4], zi, N);
  k_agg<64, true><<<dim3((N + 3) / 4), dim3(256), 0, stream>>>(
      h3, offs, csr, ssrc, sdst, &gm[4], zi, b3, Wr, br, (float*)d_out, N);
}

// Round 10
// 496.507 us; speedup vs baseline: 1.1676x; 1.0420x over previous
//
#include <hip/hip_runtime.h>
#include <hip/hip_bf16.h>
#include <cstdint>
#include <cstddef>

#define NEG_SLOPE 0.2f

typedef short short8 __attribute__((ext_vector_type(8)));
typedef float f32x4 __attribute__((ext_vector_type(4)));
typedef unsigned short ushort4v __attribute__((ext_vector_type(4)));

__device__ __forceinline__ float lrelu(float x){ return x > 0.f ? x : NEG_SLOPE * x; }
// fast ELU: __expf is HW v_exp_f32; abs err ~6e-8, far below bf16 rounding in this path
__device__ __forceinline__ float eluf(float x){ return x > 0.f ? x : __expf(x) - 1.f; }

__device__ __forceinline__ unsigned short f2bf(float f){
  union { float f; unsigned int u; } v; v.f = f;
  unsigned int r = (v.u + 0x7fff + ((v.u >> 16) & 1)) >> 16;  // RNE
  return (unsigned short)r;
}

// order-preserving float<->uint for atomicMax on signed floats
__device__ __forceinline__ unsigned f2ord(float f){
  unsigned u = __float_as_uint(f);
  return (u >> 31) ? ~u : (u | 0x80000000u);
}
__device__ __forceinline__ float ord2f(unsigned o){
  return (o >> 31) ? __uint_as_float(o & 0x7FFFFFFFu) : __uint_as_float(~o);
}

__device__ __forceinline__ float wave_sum(float v){
#pragma unroll
  for (int d = 32; d > 0; d >>= 1) v += __shfl_xor(v, d, 64);
  return v;
}
__device__ __forceinline__ float wave_max(float v){
#pragma unroll
  for (int d = 32; d > 0; d >>= 1) v = fmaxf(v, __shfl_xor(v, d, 64));
  return v;
}

// ---------------- CSR build ----------------

__global__ __launch_bounds__(256) void k_zero_int(int* p, int n){
  int i = blockIdx.x * 256 + threadIdx.x;
  if (i < n) p[i] = 0;
}

__global__ __launch_bounds__(256) void k_deg(const int* __restrict__ ei, int E, int N,
                                             int* __restrict__ deg){
  int e = blockIdx.x * 256 + threadIdx.x;
  int Et = E + N;
  if (e < Et){
    int d = (e < E) ? ei[E + e] : (e - E);
    atomicAdd(&deg[d], 1);
  }
}

__global__ __launch_bounds__(256) void k_scan_local(const int* __restrict__ deg,
                                                    int* __restrict__ offs,
                                                    int* __restrict__ bsum, int n){
  __shared__ int ws4[4];
  int tid = threadIdx.x, lane = tid & 63, wid = tid >> 6;
  int base = blockIdx.x * 1024 + tid * 4;
  int v[4]; int s = 0;
#pragma unroll
  for (int j = 0; j < 4; j++){ v[j] = (base + j < n) ? deg[base + j] : 0; s += v[j]; }
  int x = s;
#pragma unroll
  for (int d = 1; d < 64; d <<= 1){ int t = __shfl_up(x, d, 64); if (lane >= d) x += t; }
  if (lane == 63) ws4[wid] = x;
  __syncthreads();
  int wbase = 0;
  for (int w = 0; w < wid; w++) wbase += ws4[w];
  int run = wbase + x - s;
#pragma unroll
  for (int j = 0; j < 4; j++){
    if (base + j < n) offs[base + j] = run;
    run += v[j];
  }
  if (tid == 0) bsum[blockIdx.x] = ws4[0] + ws4[1] + ws4[2] + ws4[3];
}

__global__ void k_scan_sums(const int* __restrict__ bsum, int* __restrict__ bbase,
                            int* __restrict__ offs, int n, int nb){
  int lane = threadIdx.x;
  int v = (lane < nb) ? bsum[lane] : 0;
  int x = v;
#pragma unroll
  for (int d = 1; d < 64; d <<= 1){ int t = __shfl_up(x, d, 64); if (lane >= d) x += t; }
  if (lane < nb) bbase[lane] = x - v;
  int total = __shfl(x, nb - 1, 64);
  if (lane == 0) offs[n] = total;
}

__global__ __launch_bounds__(256) void k_scan_add(int* __restrict__ offs,
                                                  const int* __restrict__ bbase, int n){
  int i = blockIdx.x * 256 + threadIdx.x;
  if (i < n) offs[i] += bbase[i >> 10];
}

__global__ __launch_bounds__(256) void k_scatter(const int* __restrict__ ei, int E, int N,
                                                 const int* __restrict__ offs,
                                                 int* __restrict__ cursor,
                                                 int* __restrict__ csr){
  int e = blockIdx.x * 256 + threadIdx.x;
  int Et = E + N;
  if (e < Et){
    int d = (e < E) ? ei[E + e] : (e - E);
    int s = (e < E) ? ei[e]     : (e - E);
    int p = atomicAdd(&cursor[d], 1);
    csr[offs[d] + p] = s;
  }
}

// ---------------- global max reduce ----------------

__global__ __launch_bounds__(256) void k_gmax(const float* __restrict__ a,
                                              unsigned* __restrict__ out, int n){
  int i = blockIdx.x * 256 + threadIdx.x;
  int stride = gridDim.x * 256;
  float m = -1e30f;
  for (; i < n; i += stride) m = fmaxf(m, a[i]);
  m = wave_max(m);
  if ((threadIdx.x & 63) == 0) atomicMax(out, f2ord(m));
}

// ---------------- layer 1 ----------------

__global__ __launch_bounds__(256) void k_uvec1(const float* __restrict__ W1,
                                               const float* __restrict__ as1,
                                               const float* __restrict__ ad1,
                                               float* __restrict__ us,
                                               float* __restrict__ ud){
  for (int id = threadIdx.x; id < 528; id += 256){
    int c = id >> 3, h = id & 7;
    const float* wrow = W1 + (size_t)c * 1024 + h * 128;
    float s0 = 0.f, s1 = 0.f;
    for (int m = 0; m < 128; m++){
      float w = wrow[m];
      s0 = fmaf(w, as1[h * 128 + m], s0);
      s1 = fmaf(w, ad1[h * 128 + m], s1);
    }
    us[id] = s0; ud[id] = s1;
  }
}

__global__ __launch_bounds__(256) void k_escore1(const float* __restrict__ x,
                                                 const float* __restrict__ us,
                                                 const float* __restrict__ ud,
                                                 float* __restrict__ ssrc,
                                                 float* __restrict__ sdst, int N){
  int wid = threadIdx.x >> 6, lane = threadIdx.x & 63;
  int n = blockIdx.x * 4 + wid;
  if (n >= N) return;
  float xv0 = x[(size_t)n * 66 + lane];
  int c1 = (lane < 2) ? 64 + lane : 0;
  float xv1 = (lane < 2) ? x[(size_t)n * 66 + c1] : 0.f;
  float es[8], ed[8];
#pragma unroll
  for (int h = 0; h < 8; h++){
    es[h] = xv0 * us[lane * 8 + h] + xv1 * us[c1 * 8 + h];
    ed[h] = xv0 * ud[lane * 8 + h] + xv1 * ud[c1 * 8 + h];
  }
#pragma unroll
  for (int h = 0; h < 8; h++){ es[h] = wave_sum(es[h]); ed[h] = wave_sum(ed[h]); }
  if (lane == 0){
#pragma unroll
    for (int h = 0; h < 8; h++){ ssrc[n * 8 + h] = es[h]; sdst[n * 8 + h] = ed[h]; }
  }
}

// one node per THREAD: single gather pass; unnormalized w -> alp, zinv per (node,head)
__global__ __launch_bounds__(256) void k_alpha1(const int* __restrict__ offs,
                                                const int* __restrict__ csr,
                                                const float* __restrict__ ssrc,
                                                const float* __restrict__ sdst,
                                                const unsigned* __restrict__ gm,
                                                float* __restrict__ alp,
                                                float* __restrict__ zinv, int N){
  int n = blockIdx.x * 256 + threadIdx.x;
  if (n >= N) return;
  float M = lrelu(ord2f(gm[0]) + ord2f(gm[1]));
  float4 sd0 = *(const float4*)&sdst[(size_t)n * 8];
  float4 sd1 = *(const float4*)&sdst[(size_t)n * 8 + 4];
  float z[8];
#pragma unroll
  for (int h = 0; h < 8; h++) z[h] = 0.f;
  int o0 = offs[n], o1 = offs[n + 1];
  for (int j = o0; j < o1; j++){
    int s = csr[j];
    float4 a0 = *(const float4*)&ssrc[(size_t)s * 8];
    float4 a1 = *(const float4*)&ssrc[(size_t)s * 8 + 4];
    float4 w0, w1;
    w0.x = __expf(lrelu(a0.x + sd0.x) - M);
    w0.y = __expf(lrelu(a0.y + sd0.y) - M);
    w0.z = __expf(lrelu(a0.z + sd0.z) - M);
    w0.w = __expf(lrelu(a0.w + sd0.w) - M);
    w1.x = __expf(lrelu(a1.x + sd1.x) - M);
    w1.y = __expf(lrelu(a1.y + sd1.y) - M);
    w1.z = __expf(lrelu(a1.z + sd1.z) - M);
    w1.w = __expf(lrelu(a1.w + sd1.w) - M);
    z[0] += w0.x; z[1] += w0.y; z[2] += w0.z; z[3] += w0.w;
    z[4] += w1.x; z[5] += w1.y; z[6] += w1.z; z[7] += w1.w;
    *(float4*)&alp[(size_t)j * 8]     = w0;
    *(float4*)&alp[(size_t)j * 8 + 4] = w1;
  }
  float4 zi0, zi1;
  zi0.x = 1.f / (z[0] + 1e-16f); zi0.y = 1.f / (z[1] + 1e-16f);
  zi0.z = 1.f / (z[2] + 1e-16f); zi0.w = 1.f / (z[3] + 1e-16f);
  zi1.x = 1.f / (z[4] + 1e-16f); zi1.y = 1.f / (z[5] + 1e-16f);
  zi1.z = 1.f / (z[6] + 1e-16f); zi1.w = 1.f / (z[7] + 1e-16f);
  *(float4*)&zinv[(size_t)n * 8]     = zi0;
  *(float4*)&zinv[(size_t)n * 8 + 4] = zi1;
}

// aggregate x; HEAD-MAJOR out: Xag[h][n][96] bf16, K padded to 96
__global__ __launch_bounds__(256) void k_agg1(const float* __restrict__ x,
                                              const int* __restrict__ offs,
                                              const int* __restrict__ csr,
                                              const float* __restrict__ alp,
                                              const float* __restrict__ zinv,
                                              __hip_bfloat16* __restrict__ Xag, int N){
  __shared__ float a_s[4][64][8];
  int tid = threadIdx.x, lane = tid & 63, wid = tid >> 6;
  int n = blockIdx.x * 4 + wid;
  if (n >= N) return;
  int o0 = offs[n], o1 = offs[n + 1];
  float acc[8], acc2[8];
#pragma unroll
  for (int h = 0; h < 8; h++){ acc[h] = 0.f; acc2[h] = 0.f; }
  int c1 = 64 + lane;  // lanes 0,1 only

  for (int cb = o0; cb < o1; cb += 64){
    int cnt = min(64, o1 - cb);
    int sreg = (lane < cnt) ? csr[cb + lane] : 0;
    if (lane < cnt){
      const float4* ap = (const float4*)(alp + (size_t)(cb + lane) * 8);
      *(float4*)&a_s[wid][lane][0] = ap[0];
      *(float4*)&a_s[wid][lane][4] = ap[1];
    }
    for (int jj = 0; jj < cnt; jj++){
      int s = __shfl(sreg, jj, 64);
      float xv = x[(size_t)s * 66 + lane];
      float xv2 = (lane < 2) ? x[(size_t)s * 66 + c1] : 0.f;
      float4 a0 = *(const float4*)&a_s[wid][jj][0];
      float4 a1 = *(const float4*)&a_s[wid][jj][4];
      acc[0] = fmaf(a0.x, xv, acc[0]); acc[1] = fmaf(a0.y, xv, acc[1]);
      acc[2] = fmaf(a0.z, xv, acc[2]); acc[3] = fmaf(a0.w, xv, acc[3]);
      acc[4] = fmaf(a1.x, xv, acc[4]); acc[5] = fmaf(a1.y, xv, acc[5]);
      acc[6] = fmaf(a1.z, xv, acc[6]); acc[7] = fmaf(a1.w, xv, acc[7]);
      if (lane < 2){
        acc2[0] = fmaf(a0.x, xv2, acc2[0]); acc2[1] = fmaf(a0.y, xv2, acc2[1]);
        acc2[2] = fmaf(a0.z, xv2, acc2[2]); acc2[3] = fmaf(a0.w, xv2, acc2[3]);
        acc2[4] = fmaf(a1.x, xv2, acc2[4]); acc2[5] = fmaf(a1.y, xv2, acc2[5]);
        acc2[6] = fmaf(a1.z, xv2, acc2[6]); acc2[7] = fmaf(a1.w, xv2, acc2[7]);
      }
    }
  }

  float zi[8];
#pragma unroll
  for (int h = 0; h < 8; h++) zi[h] = zinv[(size_t)n * 8 + h];

  size_t slab = (size_t)N * 96;
#pragma unroll
  for (int h = 0; h < 8; h++)
    Xag[(size_t)h * slab + (size_t)n * 96 + lane] = __float2bfloat16(acc[h] * zi[h]);
  if (lane < 32){
    __hip_bfloat16 zero = __float2bfloat16(0.f);
#pragma unroll
    for (int h = 0; h < 8; h++)
      Xag[(size_t)h * slab + (size_t)n * 96 + 64 + lane] =
          (lane < 2) ? __float2bfloat16(acc2[h] * zi[h]) : zero;
  }
}

// W1 repack: W1rep[h][col][k] bf16, k in [0,96) zero-padded past 66
__global__ __launch_bounds__(256) void k_w1rep(const float* __restrict__ W1,
                                               __hip_bfloat16* __restrict__ W1rep){
  int id = blockIdx.x * 256 + threadIdx.x;
  if (id >= 8 * 128 * 96) return;
  int k = id % 96;
  int rc = id / 96;
  int col = rc & 127, h = rc >> 7;
  float v = (k < 66) ? W1[(size_t)k * 1024 + h * 128 + col] : 0.f;
  W1rep[id] = __float2bfloat16(v);
}

// layer-1 projection: barrier-free MFMA (head-major Xag, 192B rows -> full-line
// fragment reads) + LDS-transposed epilogue (coalesced stores), fast ELU
__global__ __launch_bounds__(256) void k_gemm1_mfma(const __hip_bfloat16* __restrict__ Xag,
                                                    const __hip_bfloat16* __restrict__ W1rep,
                                                    const float* __restrict__ b1,
                                                    __hip_bfloat16* __restrict__ B, int N){
  __shared__ short ob[128 * 136];
  int tid = threadIdx.x, lane = tid & 63, w = tid >> 6;
  int r0 = blockIdx.x * 128;
  int h  = blockIdx.y;
  int wm = (w >> 1) * 64;
  int wn = (w & 1) * 64;
  int n15 = lane & 15, q = lane >> 4;
  f32x4 acc[4][4];
#pragma unroll
  for (int mi = 0; mi < 4; mi++)
#pragma unroll
    for (int ni = 0; ni < 4; ni++) acc[mi][ni] = (f32x4){0.f, 0.f, 0.f, 0.f};

  const short* Xh = (const short*)Xag + (size_t)h * N * 96;   // head slab
  const short* Wg = (const short*)W1rep;

  int nodes[4];
#pragma unroll
  for (int t = 0; t < 4; t++){
    int nd = r0 + wn + t * 16 + n15;
    nodes[t] = (nd < N) ? nd : (N - 1);
  }

#pragma unroll
  for (int ks = 0; ks < 3; ks++){
    int k0 = ks * 32 + q * 8;
    short8 wf[4], xf[4];
#pragma unroll
    for (int t = 0; t < 4; t++){
      wf[t] = *(const short8*)&Wg[((size_t)h * 128 + wm + t * 16 + n15) * 96 + k0];
      xf[t] = *(const short8*)&Xh[(size_t)nodes[t] * 96 + k0];
    }
#pragma unroll
    for (int mi = 0; mi < 4; mi++)
#pragma unroll
      for (int ni = 0; ni < 4; ni++)
        acc[mi][ni] = __builtin_amdgcn_mfma_f32_16x16x32_bf16(wf[mi], xf[ni], acc[mi][ni], 0, 0, 0);
  }

#pragma unroll
  for (int mi = 0; mi < 4; mi++){
    int c0 = wm + mi * 16 + q * 4;
    float4 bb = *(const float4*)&b1[h * 128 + c0];
#pragma unroll
    for (int ni = 0; ni < 4; ni++){
      int nrow = wn + ni * 16 + n15;
      ushort4v o;
      o.x = f2bf(eluf(acc[mi][ni][0] + bb.x));
      o.y = f2bf(eluf(acc[mi][ni][1] + bb.y));
      o.z = f2bf(eluf(acc[mi][ni][2] + bb.z));
      o.w = f2bf(eluf(acc[mi][ni][3] + bb.w));
      *(ushort4v*)&ob[nrow * 136 + c0] = o;
    }
  }
  __syncthreads();

#pragma unroll
  for (int p = 0; p < 8; p++){
    int c = p * 256 + tid;
    int row = c >> 4, ch = c & 15;
    int node = r0 + row;
    if (node < N){
      short8 v = *(const short8*)&ob[row * 136 + ch * 8];
      *(short8*)((unsigned short*)B + (size_t)node * 1024 + h * 128 + ch * 8) = v;
    }
  }
}

// ---------------- W2 transpose + bf16 ----------------

__global__ __launch_bounds__(256) void k_w2t(const float* __restrict__ W2,
                                             __hip_bfloat16* __restrict__ W2T){
  int id = blockIdx.x * 256 + threadIdx.x;
  int k = id >> 7, n = id & 127;
  W2T[(size_t)n * 1024 + k] = __float2bfloat16(W2[id]);
}

// ---------------- layer 2 GEMM: LDS-staged, operand-swapped ----------------

__global__ __launch_bounds__(256) void k_gemm2_mfma(const __hip_bfloat16* __restrict__ Abf,
                                                    const __hip_bfloat16* __restrict__ W2T,
                                                    float* __restrict__ C, int N){
  __shared__ short As[128 * 32];
  __shared__ short Ws[128 * 32];
  int tid = threadIdx.x, lane = tid & 63, w = tid >> 6;
  int r0 = blockIdx.x * 128;
  int wm = (w >> 1) * 64;
  int wn = (w & 1) * 64;
  f32x4 acc[4][4];
#pragma unroll
  for (int mi = 0; mi < 4; mi++)
#pragma unroll
    for (int ni = 0; ni < 4; ni++) acc[mi][ni] = (f32x4){0.f, 0.f, 0.f, 0.f};

  const short* Ag = (const short*)Abf;
  const short* Bg = (const short*)W2T;

  for (int kt = 0; kt < 1024; kt += 32){
    __syncthreads();
#pragma unroll
    for (int p = 0; p < 2; p++){
      int i = p * 256 + tid;
      int row = i >> 2, c = i & 3;
      int rg = r0 + row; if (rg > N - 1) rg = N - 1;
      const short* gp = Ag + (size_t)rg * 1024 + kt + c * 8;
      __builtin_amdgcn_global_load_lds((const __attribute__((address_space(1))) void*)gp,
                                       (__attribute__((address_space(3))) void*)&As[i * 8],
                                       16, 0, 0);
      const short* gq = Bg + (size_t)row * 1024 + kt + c * 8;
      __builtin_amdgcn_global_load_lds((const __attribute__((address_space(1))) void*)gq,
                                       (__attribute__((address_space(3))) void*)&Ws[i * 8],
                                       16, 0, 0);
    }
    __syncthreads();
    int ko = (lane >> 4) * 8;
    short8 wf[4], xf[4];
#pragma unroll
    for (int t = 0; t < 4; t++){
      wf[t] = *(const short8*)&Ws[(wm + t * 16 + (lane & 15)) * 32 + ko];
      xf[t] = *(const short8*)&As[(wn + t * 16 + (lane & 15)) * 32 + ko];
    }
#pragma unroll
    for (int mi = 0; mi < 4; mi++)
#pragma unroll
      for (int ni = 0; ni < 4; ni++)
        acc[mi][ni] = __builtin_amdgcn_mfma_f32_16x16x32_bf16(wf[mi], xf[ni], acc[mi][ni], 0, 0, 0);
  }

  int n15 = lane & 15, q = lane >> 4;
#pragma unroll
  for (int mi = 0; mi < 4; mi++){
    int c0 = wm + mi * 16 + q * 4;
#pragma unroll
    for (int ni = 0; ni < 4; ni++){
      int node = r0 + wn + ni * 16 + n15;
      if (node < N) *(f32x4*)&C[(size_t)node * 128 + c0] = acc[mi][ni];
    }
  }
}

// ---------------- narrow GEMM (layer 3): fp32 ----------------

template<int M, int K, int KT>
__global__ __launch_bounds__(256) void k_gemm_n(const float* __restrict__ X,
                                                const float* __restrict__ W,
                                                float* __restrict__ O, int N){
  constexpr int G  = 256 / M;
  constexpr int R  = 16;
  constexpr int RB = G * R;
  __shared__ __align__(16) float xs[RB][KT];
  int tid = threadIdx.x;
  int g = tid / M, col = tid - g * M;
  int r0 = blockIdx.x * RB;
  float acc[R];
#pragma unroll
  for (int r = 0; r < R; r++) acc[r] = 0.f;
  for (int kt = 0; kt < K; kt += KT){
    __syncthreads();
    for (int i = tid; i < RB * KT; i += 256){
      int r = i / KT, k = i - r * KT;
      int row = r0 + r;
      xs[r][k] = (row < N) ? X[(size_t)row * K + kt + k] : 0.f;
    }
    __syncthreads();
    for (int kk = 0; kk < KT; kk += 4){
      float w0 = W[(kt + kk)     * M + col];
      float w1 = W[(kt + kk + 1) * M + col];
      float w2 = W[(kt + kk + 2) * M + col];
      float w3 = W[(kt + kk + 3) * M + col];
#pragma unroll
      for (int r = 0; r < R; r++){
        float4 xv = *(const float4*)&xs[g * R + r][kk];
        acc[r] = fmaf(xv.x, w0, fmaf(xv.y, w1, fmaf(xv.z, w2, fmaf(xv.w, w3, acc[r]))));
      }
    }
  }
  for (int r = 0; r < R; r++){
    int row = r0 + g * R + r;
    if (row < N) O[(size_t)row * M + col] = acc[r];
  }
}

// ---------------- attention dots + z + aggregation (layers 2,3) ----------------

template<int C>
__global__ __launch_bounds__(256) void k_dots(const float* __restrict__ Hb,
                                              const float* __restrict__ Asrc,
                                              const float* __restrict__ Adst,
                                              float* __restrict__ Ssrc,
                                              float* __restrict__ Sdst, int N){
  int wid = threadIdx.x >> 6, lane = threadIdx.x & 63;
  int n = blockIdx.x * 4 + wid;
  if (n >= N) return;
  const float* hp = Hb + (size_t)n * C;
  float as_ = 0.f, ad_ = 0.f;
#pragma unroll
  for (int c = lane; c < C; c += 64){
    float hv = hp[c];
    as_ += hv * Asrc[c];
    ad_ += hv * Adst[c];
  }
  as_ = wave_sum(as_);
  ad_ = wave_sum(ad_);
  if (lane == 0){ Ssrc[n] = as_; Sdst[n] = ad_; }
}

__global__ __launch_bounds__(256) void k_zed(const int* __restrict__ offs,
                                             const int* __restrict__ csr,
                                             const float* __restrict__ Ssrc,
                                             const float* __restrict__ Sdst,
                                             const unsigned* __restrict__ gm,
                                             float* __restrict__ zinv, int N){
  int n = blockIdx.x * 256 + threadIdx.x;
  if (n >= N) return;
  float M = lrelu(ord2f(gm[0]) + ord2f(gm[1]));
  float sd = Sdst[n];
  float z = 0.f;
  int o0 = offs[n], o1 = offs[n + 1];
  for (int j = o0; j < o1; j++)
    z += __expf(lrelu(Ssrc[csr[j]] + sd) - M);
  zinv[n] = 1.f / (z + 1e-16f);
}

template<int C, bool FINAL>
__global__ __launch_bounds__(256) void k_agg(const float* __restrict__ Hb,
                                             const int* __restrict__ offs,
                                             const int* __restrict__ csr,
                                             const float* __restrict__ Ssrc,
                                             const float* __restrict__ Sdst,
                                             const unsigned* __restrict__ gm,
                                             const float* __restrict__ zinv,
                                             const float* __restrict__ bias,
                                             const float* __restrict__ Wr,
                                             const float* __restrict__ br,
                                             float* __restrict__ Out, int N){
  int wid = threadIdx.x >> 6, lane = threadIdx.x & 63;
  int n = blockIdx.x * 4 + wid;
  if (n >= N) return;
  int o0 = offs[n], o1 = offs[n + 1];
  float M = lrelu(ord2f(gm[0]) + ord2f(gm[1]));
  float sd = Sdst[n];
  float iz = zinv[n];

  constexpr int CP = C / 64;
  float acc[CP];
#pragma unroll
  for (int r = 0; r < CP; r++) acc[r] = 0.f;

  for (int j = o0; j < o1; j++){
    int s = csr[j];
    float w = __expf(lrelu(Ssrc[s] + sd) - M);
    const float* hp = Hb + (size_t)s * C;
#pragma unroll
    for (int r = 0; r < CP; r++) acc[r] = fmaf(w, hp[lane + r * 64], acc[r]);
  }

  if (!FINAL){
#pragma unroll
    for (int r = 0; r < CP; r++){
      int c = lane + r * 64;
      Out[(size_t)n * C + c] = eluf(acc[r] * iz + bias[c]);
    }
  } else {
    float v = eluf(acc[0] * iz + bias[lane]);
    float t = wave_sum(v * Wr[lane]);
    if (lane == 0) Out[n] = 1.f / (1.f + __expf(-(t + br[0])));
  }
}

// ---------------- host launch ----------------

extern "C" void kernel_launch(void* const* d_in, const int* in_sizes, int n_in,
                              void* d_out, int out_size, void* d_ws, size_t ws_size,
                              hipStream_t stream){
  const float* x   = (const float*)d_in[0];
  const int*   ei  = (const int*)  d_in[1];
  const float* W1  = (const float*)d_in[2];
  const float* as1 = (const float*)d_in[3];
  const float* ad1 = (const float*)d_in[4];
  const float* b1  = (const float*)d_in[5];
  const float* W2  = (const float*)d_in[6];
  const float* as2 = (const float*)d_in[7];
  const float* ad2 = (const float*)d_in[8];
  const float* b2  = (const float*)d_in[9];
  const float* W3  = (const float*)d_in[10];
  const float* as3 = (const float*)d_in[11];
  const float* ad3 = (const float*)d_in[12];
  const float* b3  = (const float*)d_in[13];
  const float* Wr  = (const float*)d_in[14];
  const float* br  = (const float*)d_in[15];

  const int N  = in_sizes[0] / 66;
  const int E  = in_sizes[1] / 2;
  const int Et = E + N;
  const int NB = (N + 1023) / 1024;
  const int NT = (N + 255) / 256;

  size_t off = 0;
  auto take = [&](size_t bytes) -> void* {
    void* p = (char*)d_ws + off;
    off = (off + bytes + 255) & ~(size_t)255;
    return p;
  };
  int*   deg    = (int*)take((size_t)2 * N * 4);
  int*   cursor = deg + N;
  int*   offs   = (int*)take((size_t)(N + 1) * 4);
  int*   csr    = (int*)take((size_t)Et * 4);
  int*   bsum   = (int*)take(64 * 4);
  int*   bbase  = (int*)take(64 * 4);
  unsigned* gm  = (unsigned*)take(8 * 4);
  float* ssrc   = (float*)take((size_t)N * 8 * 4);
  float* sdst   = (float*)take((size_t)N * 8 * 4);
  float* zi     = (float*)take((size_t)N * 8 * 4);
  float* us     = (float*)take(528 * 4);
  float* ud     = (float*)take(528 * 4);
  __hip_bfloat16* W2T   = (__hip_bfloat16*)take((size_t)128 * 1024 * 2);
  __hip_bfloat16* W1rep = (__hip_bfloat16*)take((size_t)8 * 128 * 96 * 2);
  float* alp    = (float*)take((size_t)Et * 8 * 4);
  size_t xag_bytes = (size_t)N * 8 * 96 * 2;
  size_t h2o_bytes = (size_t)N * 128 * 4 * 2;
  void*  U = take(xag_bytes > h2o_bytes ? xag_bytes : h2o_bytes);
  __hip_bfloat16* Xag = (__hip_bfloat16*)U;
  float* h2   = (float*)U;
  float* out2 = (float*)((char*)U + (size_t)N * 128 * 4);
  __hip_bfloat16* B = (__hip_bfloat16*)take((size_t)N * 1024 * 2);
  float* h3 = h2;
  (void)ws_size; (void)n_in; (void)out_size;

  // CSR build + init
  k_zero_int<<<dim3((2 * N + 255) / 256), dim3(256), 0, stream>>>(deg, 2 * N);
  k_zero_int<<<dim3(1), dim3(256), 0, stream>>>((int*)gm, 8);
  k_deg<<<dim3((Et + 255) / 256), dim3(256), 0, stream>>>(ei, E, N, deg);
  k_scan_local<<<dim3(NB), dim3(256), 0, stream>>>(deg, offs, bsum, N);
  k_scan_sums<<<dim3(1), dim3(64), 0, stream>>>(bsum, bbase, offs, N, NB);
  k_scan_add<<<dim3((N + 255) / 256), dim3(256), 0, stream>>>(offs, bbase, N);
  k_scatter<<<dim3((Et + 255) / 256), dim3(256), 0, stream>>>(ei, E, N, offs, cursor, csr);

  // layer 1
  k_uvec1<<<dim3(1), dim3(256), 0, stream>>>(W1, as1, ad1, us, ud);
  k_escore1<<<dim3((N + 3) / 4), dim3(256), 0, stream>>>(x, us, ud, ssrc, sdst, N);
  k_gmax<<<dim3(128), dim3(256), 0, stream>>>(ssrc, &gm[0], N * 8);
  k_gmax<<<dim3(128), dim3(256), 0, stream>>>(sdst, &gm[1], N * 8);
  k_alpha1<<<dim3(NT), dim3(256), 0, stream>>>(offs, csr, ssrc, sdst, gm, alp, zi, N);
  k_agg1<<<dim3((N + 3) / 4), dim3(256), 0, stream>>>(x, offs, csr, alp, zi, Xag, N);
  k_w1rep<<<dim3(384), dim3(256), 0, stream>>>(W1, W1rep);
  k_gemm1_mfma<<<dim3((N + 127) / 128, 8), dim3(256), 0, stream>>>(Xag, W1rep, b1, B, N);

  // layer 2
  k_w2t<<<dim3(512), dim3(256), 0, stream>>>(W2, W2T);
  k_gemm2_mfma<<<dim3((N + 127) / 128), dim3(256), 0, stream>>>(B, W2T, h2, N);
  k_dots<128><<<dim3((N + 3) / 4), dim3(256), 0, stream>>>(h2, as2, ad2, ssrc, sdst, N);
  k_gmax<<<dim3(128), dim3(256), 0, stream>>>(ssrc, &gm[2], N);
  k_gmax<<<dim3(128), dim3(256), 0, stream>>>(sdst, &gm[3], N);
  k_zed<<<dim3(NT), dim3(256), 0, stream>>>(offs, csr, ssrc, sdst, &gm[2], zi, N);
  k_agg<128, false><<<dim3((N + 3) / 4), dim3(256), 0, stream>>>(
      h2, offs, csr, ssrc, sdst, &gm[2], zi, b2, nullptr, nullptr, out2, N);

  // layer 3
  k_gemm_n<64, 128, 128><<<dim3((N + 63) / 64), dim3(256), 0, stream>>>(out2, W3, h3, N);
  k_dots<64><<<dim3((N + 3) / 4), dim3(256), 0, stream>>>(h3, as3, ad3, ssrc, sdst, N);
  k_gmax<<<dim3(128), dim3(256), 0, stream>>>(ssrc, &gm[4], N);
  k_gmax<<<dim3(128), dim3(256), 0, stream>>>(sdst, &gm[5], N);
  k_zed<<<dim3(NT), dim3(256), 0, stream>>>(offs, csr, ssrc, sdst, &gm[4], zi, N);
  k_agg<64, true><<<dim3((N + 3) / 4), dim3(256), 0, stream>>>(
      h3, offs, csr, ssrc, sdst, &gm[4], zi, b3, Wr, br, (float*)d_out, N);
}

// Round 11
// 456.283 us; speedup vs baseline: 1.2706x; 1.0882x over previous
//
#include <hip/hip_runtime.h>
#include <hip/hip_bf16.h>
#include <cstdint>
#include <cstddef>

#define NEG_SLOPE 0.2f

typedef short short8 __attribute__((ext_vector_type(8)));
typedef float f32x4 __attribute__((ext_vector_type(4)));
typedef unsigned short ushort4v __attribute__((ext_vector_type(4)));

__device__ __forceinline__ float lrelu(float x){ return x > 0.f ? x : NEG_SLOPE * x; }
// fast ELU: __expf is HW v_exp_f32; abs err ~6e-8, far below bf16 rounding in this path
__device__ __forceinline__ float eluf(float x){ return x > 0.f ? x : __expf(x) - 1.f; }

__device__ __forceinline__ unsigned short f2bf(float f){
  union { float f; unsigned int u; } v; v.f = f;
  unsigned int r = (v.u + 0x7fff + ((v.u >> 16) & 1)) >> 16;  // RNE
  return (unsigned short)r;
}

// order-preserving float<->uint for atomicMax on signed floats
__device__ __forceinline__ unsigned f2ord(float f){
  unsigned u = __float_as_uint(f);
  return (u >> 31) ? ~u : (u | 0x80000000u);
}
__device__ __forceinline__ float ord2f(unsigned o){
  return (o >> 31) ? __uint_as_float(o & 0x7FFFFFFFu) : __uint_as_float(~o);
}

__device__ __forceinline__ float wave_sum(float v){
#pragma unroll
  for (int d = 32; d > 0; d >>= 1) v += __shfl_xor(v, d, 64);
  return v;
}
__device__ __forceinline__ float wave_max(float v){
#pragma unroll
  for (int d = 32; d > 0; d >>= 1) v = fmaxf(v, __shfl_xor(v, d, 64));
  return v;
}

// ---------------- CSR build ----------------

__global__ __launch_bounds__(256) void k_zero_int(int* p, int n){
  int i = blockIdx.x * 256 + threadIdx.x;
  if (i < n) p[i] = 0;
}

__global__ __launch_bounds__(256) void k_deg(const int* __restrict__ ei, int E, int N,
                                             int* __restrict__ deg){
  int e = blockIdx.x * 256 + threadIdx.x;
  int Et = E + N;
  if (e < Et){
    int d = (e < E) ? ei[E + e] : (e - E);
    atomicAdd(&deg[d], 1);
  }
}

__global__ __launch_bounds__(256) void k_scan_local(const int* __restrict__ deg,
                                                    int* __restrict__ offs,
                                                    int* __restrict__ bsum, int n){
  __shared__ int ws4[4];
  int tid = threadIdx.x, lane = tid & 63, wid = tid >> 6;
  int base = blockIdx.x * 1024 + tid * 4;
  int v[4]; int s = 0;
#pragma unroll
  for (int j = 0; j < 4; j++){ v[j] = (base + j < n) ? deg[base + j] : 0; s += v[j]; }
  int x = s;
#pragma unroll
  for (int d = 1; d < 64; d <<= 1){ int t = __shfl_up(x, d, 64); if (lane >= d) x += t; }
  if (lane == 63) ws4[wid] = x;
  __syncthreads();
  int wbase = 0;
  for (int w = 0; w < wid; w++) wbase += ws4[w];
  int run = wbase + x - s;
#pragma unroll
  for (int j = 0; j < 4; j++){
    if (base + j < n) offs[base + j] = run;
    run += v[j];
  }
  if (tid == 0) bsum[blockIdx.x] = ws4[0] + ws4[1] + ws4[2] + ws4[3];
}

__global__ void k_scan_sums(const int* __restrict__ bsum, int* __restrict__ bbase,
                            int* __restrict__ offs, int n, int nb){
  int lane = threadIdx.x;
  int v = (lane < nb) ? bsum[lane] : 0;
  int x = v;
#pragma unroll
  for (int d = 1; d < 64; d <<= 1){ int t = __shfl_up(x, d, 64); if (lane >= d) x += t; }
  if (lane < nb) bbase[lane] = x - v;
  int total = __shfl(x, nb - 1, 64);
  if (lane == 0) offs[n] = total;
}

__global__ __launch_bounds__(256) void k_scan_add(int* __restrict__ offs,
                                                  const int* __restrict__ bbase, int n){
  int i = blockIdx.x * 256 + threadIdx.x;
  if (i < n) offs[i] += bbase[i >> 10];
}

__global__ __launch_bounds__(256) void k_scatter(const int* __restrict__ ei, int E, int N,
                                                 const int* __restrict__ offs,
                                                 int* __restrict__ cursor,
                                                 int* __restrict__ csr){
  int e = blockIdx.x * 256 + threadIdx.x;
  int Et = E + N;
  if (e < Et){
    int d = (e < E) ? ei[E + e] : (e - E);
    int s = (e < E) ? ei[e]     : (e - E);
    int p = atomicAdd(&cursor[d], 1);
    csr[offs[d] + p] = s;
  }
}

// ---------------- global max reduce ----------------

__global__ __launch_bounds__(256) void k_gmax(const float* __restrict__ a,
                                              unsigned* __restrict__ out, int n){
  int i = blockIdx.x * 256 + threadIdx.x;
  int stride = gridDim.x * 256;
  float m = -1e30f;
  for (; i < n; i += stride) m = fmaxf(m, a[i]);
  m = wave_max(m);
  if ((threadIdx.x & 63) == 0) atomicMax(out, f2ord(m));
}

// ---------------- layer 1 ----------------

__global__ __launch_bounds__(256) void k_uvec1(const float* __restrict__ W1,
                                               const float* __restrict__ as1,
                                               const float* __restrict__ ad1,
                                               float* __restrict__ us,
                                               float* __restrict__ ud){
  for (int id = threadIdx.x; id < 528; id += 256){
    int c = id >> 3, h = id & 7;
    const float* wrow = W1 + (size_t)c * 1024 + h * 128;
    float s0 = 0.f, s1 = 0.f;
    for (int m = 0; m < 128; m++){
      float w = wrow[m];
      s0 = fmaf(w, as1[h * 128 + m], s0);
      s1 = fmaf(w, ad1[h * 128 + m], s1);
    }
    us[id] = s0; ud[id] = s1;
  }
}

// ONE NODE PER THREAD: no cross-lane ops. us/ud are wave-uniform -> scalar loads.
__global__ __launch_bounds__(256) void k_escore1(const float* __restrict__ x,
                                                 const float* __restrict__ us,
                                                 const float* __restrict__ ud,
                                                 float* __restrict__ ssrc,
                                                 float* __restrict__ sdst, int N){
  int n = blockIdx.x * 256 + threadIdx.x;
  if (n >= N) return;
  const float* xp = x + (size_t)n * 66;
  float es[8], ed[8];
#pragma unroll
  for (int h = 0; h < 8; h++){ es[h] = 0.f; ed[h] = 0.f; }
  // 66 = 33 float2 (row stride 264B is 8B-aligned)
  for (int c2 = 0; c2 < 33; c2++){
    float2 xv = *(const float2*)&xp[c2 * 2];
    int c = c2 * 2;
#pragma unroll
    for (int h = 0; h < 8; h++){
      es[h] = fmaf(xv.x, us[c * 8 + h], fmaf(xv.y, us[(c + 1) * 8 + h], es[h]));
      ed[h] = fmaf(xv.x, ud[c * 8 + h], fmaf(xv.y, ud[(c + 1) * 8 + h], ed[h]));
    }
  }
  *(float4*)&ssrc[(size_t)n * 8]     = (float4){es[0], es[1], es[2], es[3]};
  *(float4*)&ssrc[(size_t)n * 8 + 4] = (float4){es[4], es[5], es[6], es[7]};
  *(float4*)&sdst[(size_t)n * 8]     = (float4){ed[0], ed[1], ed[2], ed[3]};
  *(float4*)&sdst[(size_t)n * 8 + 4] = (float4){ed[4], ed[5], ed[6], ed[7]};
}

// one node per THREAD: single gather pass; unnormalized w -> alp, zinv per (node,head)
__global__ __launch_bounds__(256) void k_alpha1(const int* __restrict__ offs,
                                                const int* __restrict__ csr,
                                                const float* __restrict__ ssrc,
                                                const float* __restrict__ sdst,
                                                const unsigned* __restrict__ gm,
                                                float* __restrict__ alp,
                                                float* __restrict__ zinv, int N){
  int n = blockIdx.x * 256 + threadIdx.x;
  if (n >= N) return;
  float M = lrelu(ord2f(gm[0]) + ord2f(gm[1]));
  float4 sd0 = *(const float4*)&sdst[(size_t)n * 8];
  float4 sd1 = *(const float4*)&sdst[(size_t)n * 8 + 4];
  float z[8];
#pragma unroll
  for (int h = 0; h < 8; h++) z[h] = 0.f;
  int o0 = offs[n], o1 = offs[n + 1];
  for (int j = o0; j < o1; j++){
    int s = csr[j];
    float4 a0 = *(const float4*)&ssrc[(size_t)s * 8];
    float4 a1 = *(const float4*)&ssrc[(size_t)s * 8 + 4];
    float4 w0, w1;
    w0.x = __expf(lrelu(a0.x + sd0.x) - M);
    w0.y = __expf(lrelu(a0.y + sd0.y) - M);
    w0.z = __expf(lrelu(a0.z + sd0.z) - M);
    w0.w = __expf(lrelu(a0.w + sd0.w) - M);
    w1.x = __expf(lrelu(a1.x + sd1.x) - M);
    w1.y = __expf(lrelu(a1.y + sd1.y) - M);
    w1.z = __expf(lrelu(a1.z + sd1.z) - M);
    w1.w = __expf(lrelu(a1.w + sd1.w) - M);
    z[0] += w0.x; z[1] += w0.y; z[2] += w0.z; z[3] += w0.w;
    z[4] += w1.x; z[5] += w1.y; z[6] += w1.z; z[7] += w1.w;
    *(float4*)&alp[(size_t)j * 8]     = w0;
    *(float4*)&alp[(size_t)j * 8 + 4] = w1;
  }
  float4 zi0, zi1;
  zi0.x = 1.f / (z[0] + 1e-16f); zi0.y = 1.f / (z[1] + 1e-16f);
  zi0.z = 1.f / (z[2] + 1e-16f); zi0.w = 1.f / (z[3] + 1e-16f);
  zi1.x = 1.f / (z[4] + 1e-16f); zi1.y = 1.f / (z[5] + 1e-16f);
  zi1.z = 1.f / (z[6] + 1e-16f); zi1.w = 1.f / (z[7] + 1e-16f);
  *(float4*)&zinv[(size_t)n * 8]     = zi0;
  *(float4*)&zinv[(size_t)n * 8 + 4] = zi1;
}

// aggregate x; HEAD-MAJOR out: Xag[h][n][96] bf16, K padded to 96
__global__ __launch_bounds__(256) void k_agg1(const float* __restrict__ x,
                                              const int* __restrict__ offs,
                                              const int* __restrict__ csr,
                                              const float* __restrict__ alp,
                                              const float* __restrict__ zinv,
                                              __hip_bfloat16* __restrict__ Xag, int N){
  __shared__ float a_s[4][64][8];
  int tid = threadIdx.x, lane = tid & 63, wid = tid >> 6;
  int n = blockIdx.x * 4 + wid;
  if (n >= N) return;
  int o0 = offs[n], o1 = offs[n + 1];
  float acc[8], acc2[8];
#pragma unroll
  for (int h = 0; h < 8; h++){ acc[h] = 0.f; acc2[h] = 0.f; }
  int c1 = 64 + lane;  // lanes 0,1 only

  for (int cb = o0; cb < o1; cb += 64){
    int cnt = min(64, o1 - cb);
    int sreg = (lane < cnt) ? csr[cb + lane] : 0;
    if (lane < cnt){
      const float4* ap = (const float4*)(alp + (size_t)(cb + lane) * 8);
      *(float4*)&a_s[wid][lane][0] = ap[0];
      *(float4*)&a_s[wid][lane][4] = ap[1];
    }
    for (int jj = 0; jj < cnt; jj++){
      int s = __shfl(sreg, jj, 64);
      float xv = x[(size_t)s * 66 + lane];
      float xv2 = (lane < 2) ? x[(size_t)s * 66 + c1] : 0.f;
      float4 a0 = *(const float4*)&a_s[wid][jj][0];
      float4 a1 = *(const float4*)&a_s[wid][jj][4];
      acc[0] = fmaf(a0.x, xv, acc[0]); acc[1] = fmaf(a0.y, xv, acc[1]);
      acc[2] = fmaf(a0.z, xv, acc[2]); acc[3] = fmaf(a0.w, xv, acc[3]);
      acc[4] = fmaf(a1.x, xv, acc[4]); acc[5] = fmaf(a1.y, xv, acc[5]);
      acc[6] = fmaf(a1.z, xv, acc[6]); acc[7] = fmaf(a1.w, xv, acc[7]);
      if (lane < 2){
        acc2[0] = fmaf(a0.x, xv2, acc2[0]); acc2[1] = fmaf(a0.y, xv2, acc2[1]);
        acc2[2] = fmaf(a0.z, xv2, acc2[2]); acc2[3] = fmaf(a0.w, xv2, acc2[3]);
        acc2[4] = fmaf(a1.x, xv2, acc2[4]); acc2[5] = fmaf(a1.y, xv2, acc2[5]);
        acc2[6] = fmaf(a1.z, xv2, acc2[6]); acc2[7] = fmaf(a1.w, xv2, acc2[7]);
      }
    }
  }

  float zi[8];
#pragma unroll
  for (int h = 0; h < 8; h++) zi[h] = zinv[(size_t)n * 8 + h];

  size_t slab = (size_t)N * 96;
#pragma unroll
  for (int h = 0; h < 8; h++)
    Xag[(size_t)h * slab + (size_t)n * 96 + lane] = __float2bfloat16(acc[h] * zi[h]);
  if (lane < 32){
    __hip_bfloat16 zero = __float2bfloat16(0.f);
#pragma unroll
    for (int h = 0; h < 8; h++)
      Xag[(size_t)h * slab + (size_t)n * 96 + 64 + lane] =
          (lane < 2) ? __float2bfloat16(acc2[h] * zi[h]) : zero;
  }
}

// W1 repack: W1rep[h][col][k] bf16, k in [0,96) zero-padded past 66
__global__ __launch_bounds__(256) void k_w1rep(const float* __restrict__ W1,
                                               __hip_bfloat16* __restrict__ W1rep){
  int id = blockIdx.x * 256 + threadIdx.x;
  if (id >= 8 * 128 * 96) return;
  int k = id % 96;
  int rc = id / 96;
  int col = rc & 127, h = rc >> 7;
  float v = (k < 66) ? W1[(size_t)k * 1024 + h * 128 + col] : 0.f;
  W1rep[id] = __float2bfloat16(v);
}

// layer-1 projection: barrier-free MFMA (head-major Xag) + LDS-transposed epilogue
__global__ __launch_bounds__(256) void k_gemm1_mfma(const __hip_bfloat16* __restrict__ Xag,
                                                    const __hip_bfloat16* __restrict__ W1rep,
                                                    const float* __restrict__ b1,
                                                    __hip_bfloat16* __restrict__ B, int N){
  __shared__ short ob[128 * 136];
  int tid = threadIdx.x, lane = tid & 63, w = tid >> 6;
  int r0 = blockIdx.x * 128;
  int h  = blockIdx.y;
  int wm = (w >> 1) * 64;
  int wn = (w & 1) * 64;
  int n15 = lane & 15, q = lane >> 4;
  f32x4 acc[4][4];
#pragma unroll
  for (int mi = 0; mi < 4; mi++)
#pragma unroll
    for (int ni = 0; ni < 4; ni++) acc[mi][ni] = (f32x4){0.f, 0.f, 0.f, 0.f};

  const short* Xh = (const short*)Xag + (size_t)h * N * 96;
  const short* Wg = (const short*)W1rep;

  int nodes[4];
#pragma unroll
  for (int t = 0; t < 4; t++){
    int nd = r0 + wn + t * 16 + n15;
    nodes[t] = (nd < N) ? nd : (N - 1);
  }

#pragma unroll
  for (int ks = 0; ks < 3; ks++){
    int k0 = ks * 32 + q * 8;
    short8 wf[4], xf[4];
#pragma unroll
    for (int t = 0; t < 4; t++){
      wf[t] = *(const short8*)&Wg[((size_t)h * 128 + wm + t * 16 + n15) * 96 + k0];
      xf[t] = *(const short8*)&Xh[(size_t)nodes[t] * 96 + k0];
    }
#pragma unroll
    for (int mi = 0; mi < 4; mi++)
#pragma unroll
      for (int ni = 0; ni < 4; ni++)
        acc[mi][ni] = __builtin_amdgcn_mfma_f32_16x16x32_bf16(wf[mi], xf[ni], acc[mi][ni], 0, 0, 0);
  }

#pragma unroll
  for (int mi = 0; mi < 4; mi++){
    int c0 = wm + mi * 16 + q * 4;
    float4 bb = *(const float4*)&b1[h * 128 + c0];
#pragma unroll
    for (int ni = 0; ni < 4; ni++){
      int nrow = wn + ni * 16 + n15;
      ushort4v o;
      o.x = f2bf(eluf(acc[mi][ni][0] + bb.x));
      o.y = f2bf(eluf(acc[mi][ni][1] + bb.y));
      o.z = f2bf(eluf(acc[mi][ni][2] + bb.z));
      o.w = f2bf(eluf(acc[mi][ni][3] + bb.w));
      *(ushort4v*)&ob[nrow * 136 + c0] = o;
    }
  }
  __syncthreads();

#pragma unroll
  for (int p = 0; p < 8; p++){
    int c = p * 256 + tid;
    int row = c >> 4, ch = c & 15;
    int node = r0 + row;
    if (node < N){
      short8 v = *(const short8*)&ob[row * 136 + ch * 8];
      *(short8*)((unsigned short*)B + (size_t)node * 1024 + h * 128 + ch * 8) = v;
    }
  }
}

// ---------------- W2 transpose + bf16 ----------------

__global__ __launch_bounds__(256) void k_w2t(const float* __restrict__ W2,
                                             __hip_bfloat16* __restrict__ W2T){
  int id = blockIdx.x * 256 + threadIdx.x;
  int k = id >> 7, n = id & 127;
  W2T[(size_t)n * 1024 + k] = __float2bfloat16(W2[id]);
}

// ---------------- layer 2 GEMM: LDS-staged, operand-swapped ----------------

__global__ __launch_bounds__(256) void k_gemm2_mfma(const __hip_bfloat16* __restrict__ Abf,
                                                    const __hip_bfloat16* __restrict__ W2T,
                                                    float* __restrict__ C, int N){
  __shared__ short As[128 * 32];
  __shared__ short Ws[128 * 32];
  int tid = threadIdx.x, lane = tid & 63, w = tid >> 6;
  int r0 = blockIdx.x * 128;
  int wm = (w >> 1) * 64;
  int wn = (w & 1) * 64;
  f32x4 acc[4][4];
#pragma unroll
  for (int mi = 0; mi < 4; mi++)
#pragma unroll
    for (int ni = 0; ni < 4; ni++) acc[mi][ni] = (f32x4){0.f, 0.f, 0.f, 0.f};

  const short* Ag = (const short*)Abf;
  const short* Bg = (const short*)W2T;

  for (int kt = 0; kt < 1024; kt += 32){
    __syncthreads();
#pragma unroll
    for (int p = 0; p < 2; p++){
      int i = p * 256 + tid;
      int row = i >> 2, c = i & 3;
      int rg = r0 + row; if (rg > N - 1) rg = N - 1;
      const short* gp = Ag + (size_t)rg * 1024 + kt + c * 8;
      __builtin_amdgcn_global_load_lds((const __attribute__((address_space(1))) void*)gp,
                                       (__attribute__((address_space(3))) void*)&As[i * 8],
                                       16, 0, 0);
      const short* gq = Bg + (size_t)row * 1024 + kt + c * 8;
      __builtin_amdgcn_global_load_lds((const __attribute__((address_space(1))) void*)gq,
                                       (__attribute__((address_space(3))) void*)&Ws[i * 8],
                                       16, 0, 0);
    }
    __syncthreads();
    int ko = (lane >> 4) * 8;
    short8 wf[4], xf[4];
#pragma unroll
    for (int t = 0; t < 4; t++){
      wf[t] = *(const short8*)&Ws[(wm + t * 16 + (lane & 15)) * 32 + ko];
      xf[t] = *(const short8*)&As[(wn + t * 16 + (lane & 15)) * 32 + ko];
    }
#pragma unroll
    for (int mi = 0; mi < 4; mi++)
#pragma unroll
      for (int ni = 0; ni < 4; ni++)
        acc[mi][ni] = __builtin_amdgcn_mfma_f32_16x16x32_bf16(wf[mi], xf[ni], acc[mi][ni], 0, 0, 0);
  }

  int n15 = lane & 15, q = lane >> 4;
#pragma unroll
  for (int mi = 0; mi < 4; mi++){
    int c0 = wm + mi * 16 + q * 4;
#pragma unroll
    for (int ni = 0; ni < 4; ni++){
      int node = r0 + wn + ni * 16 + n15;
      if (node < N) *(f32x4*)&C[(size_t)node * 128 + c0] = acc[mi][ni];
    }
  }
}

// ---------------- narrow GEMM (layer 3): fp32 ----------------

template<int M, int K, int KT>
__global__ __launch_bounds__(256) void k_gemm_n(const float* __restrict__ X,
                                                const float* __restrict__ W,
                                                float* __restrict__ O, int N){
  constexpr int G  = 256 / M;
  constexpr int R  = 16;
  constexpr int RB = G * R;
  __shared__ __align__(16) float xs[RB][KT];
  int tid = threadIdx.x;
  int g = tid / M, col = tid - g * M;
  int r0 = blockIdx.x * RB;
  float acc[R];
#pragma unroll
  for (int r = 0; r < R; r++) acc[r] = 0.f;
  for (int kt = 0; kt < K; kt += KT){
    __syncthreads();
    for (int i = tid; i < RB * KT; i += 256){
      int r = i / KT, k = i - r * KT;
      int row = r0 + r;
      xs[r][k] = (row < N) ? X[(size_t)row * K + kt + k] : 0.f;
    }
    __syncthreads();
    for (int kk = 0; kk < KT; kk += 4){
      float w0 = W[(kt + kk)     * M + col];
      float w1 = W[(kt + kk + 1) * M + col];
      float w2 = W[(kt + kk + 2) * M + col];
      float w3 = W[(kt + kk + 3) * M + col];
#pragma unroll
      for (int r = 0; r < R; r++){
        float4 xv = *(const float4*)&xs[g * R + r][kk];
        acc[r] = fmaf(xv.x, w0, fmaf(xv.y, w1, fmaf(xv.z, w2, fmaf(xv.w, w3, acc[r]))));
      }
    }
  }
  for (int r = 0; r < R; r++){
    int row = r0 + g * R + r;
    if (row < N) O[(size_t)row * M + col] = acc[r];
  }
}

// ---------------- attention dots + z + aggregation (layers 2,3) ----------------

// ONE NODE PER THREAD: no cross-lane ops; Asrc/Adst wave-uniform -> scalar loads
template<int C>
__global__ __launch_bounds__(256) void k_dots(const float* __restrict__ Hb,
                                              const float* __restrict__ Asrc,
                                              const float* __restrict__ Adst,
                                              float* __restrict__ Ssrc,
                                              float* __restrict__ Sdst, int N){
  int n = blockIdx.x * 256 + threadIdx.x;
  if (n >= N) return;
  const float* hp = Hb + (size_t)n * C;
  float as_ = 0.f, ad_ = 0.f;
  for (int c4 = 0; c4 < C / 4; c4++){
    float4 hv = *(const float4*)&hp[c4 * 4];
    int c = c4 * 4;
    as_ = fmaf(hv.x, Asrc[c],     as_); ad_ = fmaf(hv.x, Adst[c],     ad_);
    as_ = fmaf(hv.y, Asrc[c + 1], as_); ad_ = fmaf(hv.y, Adst[c + 1], ad_);
    as_ = fmaf(hv.z, Asrc[c + 2], as_); ad_ = fmaf(hv.z, Adst[c + 2], ad_);
    as_ = fmaf(hv.w, Asrc[c + 3], as_); ad_ = fmaf(hv.w, Adst[c + 3], ad_);
  }
  Ssrc[n] = as_; Sdst[n] = ad_;
}

__global__ __launch_bounds__(256) void k_zed(const int* __restrict__ offs,
                                             const int* __restrict__ csr,
                                             const float* __restrict__ Ssrc,
                                             const float* __restrict__ Sdst,
                                             const unsigned* __restrict__ gm,
                                             float* __restrict__ zinv, int N){
  int n = blockIdx.x * 256 + threadIdx.x;
  if (n >= N) return;
  float M = lrelu(ord2f(gm[0]) + ord2f(gm[1]));
  float sd = Sdst[n];
  float z = 0.f;
  int o0 = offs[n], o1 = offs[n + 1];
  for (int j = o0; j < o1; j++)
    z += __expf(lrelu(Ssrc[csr[j]] + sd) - M);
  zinv[n] = 1.f / (z + 1e-16f);
}

template<int C, bool FINAL>
__global__ __launch_bounds__(256) void k_agg(const float* __restrict__ Hb,
                                             const int* __restrict__ offs,
                                             const int* __restrict__ csr,
                                             const float* __restrict__ Ssrc,
                                             const float* __restrict__ Sdst,
                                             const unsigned* __restrict__ gm,
                                             const float* __restrict__ zinv,
                                             const float* __restrict__ bias,
                                             const float* __restrict__ Wr,
                                             const float* __restrict__ br,
                                             float* __restrict__ Out, int N){
  int wid = threadIdx.x >> 6, lane = threadIdx.x & 63;
  int n = blockIdx.x * 4 + wid;
  if (n >= N) return;
  int o0 = offs[n], o1 = offs[n + 1];
  float M = lrelu(ord2f(gm[0]) + ord2f(gm[1]));
  float sd = Sdst[n];
  float iz = zinv[n];

  constexpr int CP = C / 64;
  float acc[CP];
#pragma unroll
  for (int r = 0; r < CP; r++) acc[r] = 0.f;

  for (int j = o0; j < o1; j++){
    int s = csr[j];
    float w = __expf(lrelu(Ssrc[s] + sd) - M);
    const float* hp = Hb + (size_t)s * C;
#pragma unroll
    for (int r = 0; r < CP; r++) acc[r] = fmaf(w, hp[lane + r * 64], acc[r]);
  }

  if (!FINAL){
#pragma unroll
    for (int r = 0; r < CP; r++){
      int c = lane + r * 64;
      Out[(size_t)n * C + c] = eluf(acc[r] * iz + bias[c]);
    }
  } else {
    float v = eluf(acc[0] * iz + bias[lane]);
    float t = wave_sum(v * Wr[lane]);
    if (lane == 0) Out[n] = 1.f / (1.f + __expf(-(t + br[0])));
  }
}

// ---------------- host launch ----------------

extern "C" void kernel_launch(void* const* d_in, const int* in_sizes, int n_in,
                              void* d_out, int out_size, void* d_ws, size_t ws_size,
                              hipStream_t stream){
  const float* x   = (const float*)d_in[0];
  const int*   ei  = (const int*)  d_in[1];
  const float* W1  = (const float*)d_in[2];
  const float* as1 = (const float*)d_in[3];
  const float* ad1 = (const float*)d_in[4];
  const float* b1  = (const float*)d_in[5];
  const float* W2  = (const float*)d_in[6];
  const float* as2 = (const float*)d_in[7];
  const float* ad2 = (const float*)d_in[8];
  const float* b2  = (const float*)d_in[9];
  const float* W3  = (const float*)d_in[10];
  const float* as3 = (const float*)d_in[11];
  const float* ad3 = (const float*)d_in[12];
  const float* b3  = (const float*)d_in[13];
  const float* Wr  = (const float*)d_in[14];
  const float* br  = (const float*)d_in[15];

  const int N  = in_sizes[0] / 66;
  const int E  = in_sizes[1] / 2;
  const int Et = E + N;
  const int NB = (N + 1023) / 1024;
  const int NT = (N + 255) / 256;

  size_t off = 0;
  auto take = [&](size_t bytes) -> void* {
    void* p = (char*)d_ws + off;
    off = (off + bytes + 255) & ~(size_t)255;
    return p;
  };
  int*   deg    = (int*)take((size_t)2 * N * 4);
  int*   cursor = deg + N;
  int*   offs   = (int*)take((size_t)(N + 1) * 4);
  int*   csr    = (int*)take((size_t)Et * 4);
  int*   bsum   = (int*)take(64 * 4);
  int*   bbase  = (int*)take(64 * 4);
  unsigned* gm  = (unsigned*)take(8 * 4);
  float* ssrc   = (float*)take((size_t)N * 8 * 4);
  float* sdst   = (float*)take((size_t)N * 8 * 4);
  float* zi     = (float*)take((size_t)N * 8 * 4);
  float* us     = (float*)take(528 * 4);
  float* ud     = (float*)take(528 * 4);
  __hip_bfloat16* W2T   = (__hip_bfloat16*)take((size_t)128 * 1024 * 2);
  __hip_bfloat16* W1rep = (__hip_bfloat16*)take((size_t)8 * 128 * 96 * 2);
  float* alp    = (float*)take((size_t)Et * 8 * 4);
  size_t xag_bytes = (size_t)N * 8 * 96 * 2;
  size_t h2o_bytes = (size_t)N * 128 * 4 * 2;
  void*  U = take(xag_bytes > h2o_bytes ? xag_bytes : h2o_bytes);
  __hip_bfloat16* Xag = (__hip_bfloat16*)U;
  float* h2   = (float*)U;
  float* out2 = (float*)((char*)U + (size_t)N * 128 * 4);
  __hip_bfloat16* B = (__hip_bfloat16*)take((size_t)N * 1024 * 2);
  float* h3 = h2;
  (void)ws_size; (void)n_in; (void)out_size;

  // CSR build + init
  k_zero_int<<<dim3((2 * N + 255) / 256), dim3(256), 0, stream>>>(deg, 2 * N);
  k_zero_int<<<dim3(1), dim3(256), 0, stream>>>((int*)gm, 8);
  k_deg<<<dim3((Et + 255) / 256), dim3(256), 0, stream>>>(ei, E, N, deg);
  k_scan_local<<<dim3(NB), dim3(256), 0, stream>>>(deg, offs, bsum, N);
  k_scan_sums<<<dim3(1), dim3(64), 0, stream>>>(bsum, bbase, offs, N, NB);
  k_scan_add<<<dim3((N + 255) / 256), dim3(256), 0, stream>>>(offs, bbase, N);
  k_scatter<<<dim3((Et + 255) / 256), dim3(256), 0, stream>>>(ei, E, N, offs, cursor, csr);

  // layer 1
  k_uvec1<<<dim3(1), dim3(256), 0, stream>>>(W1, as1, ad1, us, ud);
  k_escore1<<<dim3(NT), dim3(256), 0, stream>>>(x, us, ud, ssrc, sdst, N);
  k_gmax<<<dim3(128), dim3(256), 0, stream>>>(ssrc, &gm[0], N * 8);
  k_gmax<<<dim3(128), dim3(256), 0, stream>>>(sdst, &gm[1], N * 8);
  k_alpha1<<<dim3(NT), dim3(256), 0, stream>>>(offs, csr, ssrc, sdst, gm, alp, zi, N);
  k_agg1<<<dim3((N + 3) / 4), dim3(256), 0, stream>>>(x, offs, csr, alp, zi, Xag, N);
  k_w1rep<<<dim3(384), dim3(256), 0, stream>>>(W1, W1rep);
  k_gemm1_mfma<<<dim3((N + 127) / 128, 8), dim3(256), 0, stream>>>(Xag, W1rep, b1, B, N);

  // layer 2
  k_w2t<<<dim3(512), dim3(256), 0, stream>>>(W2, W2T);
  k_gemm2_mfma<<<dim3((N + 127) / 128), dim3(256), 0, stream>>>(B, W2T, h2, N);
  k_dots<128><<<dim3(NT), dim3(256), 0, stream>>>(h2, as2, ad2, ssrc, sdst, N);
  k_gmax<<<dim3(128), dim3(256), 0, stream>>>(ssrc, &gm[2], N);
  k_gmax<<<dim3(128), dim3(256), 0, stream>>>(sdst, &gm[3], N);
  k_zed<<<dim3(NT), dim3(256), 0, stream>>>(offs, csr, ssrc, sdst, &gm[2], zi, N);
  k_agg<128, false><<<dim3((N + 3) / 4), dim3(256), 0, stream>>>(
      h2, offs, csr, ssrc, sdst, &gm[2], zi, b2, nullptr, nullptr, out2, N);

  // layer 3
  k_gemm_n<64, 128, 128><<<dim3((N + 63) / 64), dim3(256), 0, stream>>>(out2, W3, h3, N);
  k_dots<64><<<dim3(NT), dim3(256), 0, stream>>>(h3, as3, ad3, ssrc, sdst, N);
  k_gmax<<<dim3(128), dim3(256), 0, stream>>>(ssrc, &gm[4], N);
  k_gmax<<<dim3(128), dim3(256), 0, stream>>>(sdst, &gm[5], N);
  k_zed<<<dim3(NT), dim3(256), 0, stream>>>(offs, csr, ssrc, sdst, &gm[4], zi, N);
  k_agg<64, true><<<dim3((N + 3) / 4), dim3(256), 0, stream>>>(
      h3, offs, csr, ssrc, sdst, &gm[4], zi, b3, Wr, br, (float*)d_out, N);
}

// Round 12
// 415.892 us; speedup vs baseline: 1.3940x; 1.0971x over previous
//
#include <hip/hip_runtime.h>
#include <hip/hip_bf16.h>
#include <cstdint>
#include <cstddef>

#define NEG_SLOPE 0.2f

typedef short short8 __attribute__((ext_vector_type(8)));
typedef float f32x4 __attribute__((ext_vector_type(4)));
typedef unsigned short ushort4v __attribute__((ext_vector_type(4)));
typedef unsigned short ushort8v __attribute__((ext_vector_type(8)));

__device__ __forceinline__ float lrelu(float x){ return x > 0.f ? x : NEG_SLOPE * x; }
__device__ __forceinline__ float eluf(float x){ return x > 0.f ? x : __expf(x) - 1.f; }

__device__ __forceinline__ unsigned short f2bf(float f){
  union { float f; unsigned int u; } v; v.f = f;
  unsigned int r = (v.u + 0x7fff + ((v.u >> 16) & 1)) >> 16;  // RNE
  return (unsigned short)r;
}
__device__ __forceinline__ float b2f(unsigned short u){
  return __uint_as_float((unsigned)u << 16);
}

// order-preserving float<->uint for atomicMax on signed floats
__device__ __forceinline__ unsigned f2ord(float f){
  unsigned u = __float_as_uint(f);
  return (u >> 31) ? ~u : (u | 0x80000000u);
}
__device__ __forceinline__ float ord2f(unsigned o){
  return (o >> 31) ? __uint_as_float(o & 0x7FFFFFFFu) : __uint_as_float(~o);
}

__device__ __forceinline__ float wave_sum(float v){
#pragma unroll
  for (int d = 32; d > 0; d >>= 1) v += __shfl_xor(v, d, 64);
  return v;
}
__device__ __forceinline__ float wave_max(float v){
#pragma unroll
  for (int d = 32; d > 0; d >>= 1) v = fmaxf(v, __shfl_xor(v, d, 64));
  return v;
}

// ---------------- CSR build ----------------

__global__ __launch_bounds__(256) void k_zero_int(int* p, int n){
  int i = blockIdx.x * 256 + threadIdx.x;
  if (i < n) p[i] = 0;
}

__global__ __launch_bounds__(256) void k_deg(const int* __restrict__ ei, int E, int N,
                                             int* __restrict__ deg){
  int e = blockIdx.x * 256 + threadIdx.x;
  int Et = E + N;
  if (e < Et){
    int d = (e < E) ? ei[E + e] : (e - E);
    atomicAdd(&deg[d], 1);
  }
}

__global__ __launch_bounds__(256) void k_scan_local(const int* __restrict__ deg,
                                                    int* __restrict__ offs,
                                                    int* __restrict__ bsum, int n){
  __shared__ int ws4[4];
  int tid = threadIdx.x, lane = tid & 63, wid = tid >> 6;
  int base = blockIdx.x * 1024 + tid * 4;
  int v[4]; int s = 0;
#pragma unroll
  for (int j = 0; j < 4; j++){ v[j] = (base + j < n) ? deg[base + j] : 0; s += v[j]; }
  int x = s;
#pragma unroll
  for (int d = 1; d < 64; d <<= 1){ int t = __shfl_up(x, d, 64); if (lane >= d) x += t; }
  if (lane == 63) ws4[wid] = x;
  __syncthreads();
  int wbase = 0;
  for (int w = 0; w < wid; w++) wbase += ws4[w];
  int run = wbase + x - s;
#pragma unroll
  for (int j = 0; j < 4; j++){
    if (base + j < n) offs[base + j] = run;
    run += v[j];
  }
  if (tid == 0) bsum[blockIdx.x] = ws4[0] + ws4[1] + ws4[2] + ws4[3];
}

__global__ void k_scan_sums(const int* __restrict__ bsum, int* __restrict__ bbase,
                            int* __restrict__ offs, int n, int nb){
  int lane = threadIdx.x;
  int v = (lane < nb) ? bsum[lane] : 0;
  int x = v;
#pragma unroll
  for (int d = 1; d < 64; d <<= 1){ int t = __shfl_up(x, d, 64); if (lane >= d) x += t; }
  if (lane < nb) bbase[lane] = x - v;
  int total = __shfl(x, nb - 1, 64);
  if (lane == 0) offs[n] = total;
}

__global__ __launch_bounds__(256) void k_scan_add(int* __restrict__ offs,
                                                  const int* __restrict__ bbase, int n){
  int i = blockIdx.x * 256 + threadIdx.x;
  if (i < n) offs[i] += bbase[i >> 10];
}

__global__ __launch_bounds__(256) void k_scatter(const int* __restrict__ ei, int E, int N,
                                                 const int* __restrict__ offs,
                                                 int* __restrict__ cursor,
                                                 int* __restrict__ csr){
  int e = blockIdx.x * 256 + threadIdx.x;
  int Et = E + N;
  if (e < Et){
    int d = (e < E) ? ei[E + e] : (e - E);
    int s = (e < E) ? ei[e]     : (e - E);
    int p = atomicAdd(&cursor[d], 1);
    csr[offs[d] + p] = s;
  }
}

// ---------------- layer 1 ----------------

__global__ __launch_bounds__(256) void k_uvec1(const float* __restrict__ W1,
                                               const float* __restrict__ as1,
                                               const float* __restrict__ ad1,
                                               float* __restrict__ us,
                                               float* __restrict__ ud){
  for (int id = threadIdx.x; id < 528; id += 256){
    int c = id >> 3, h = id & 7;
    const float* wrow = W1 + (size_t)c * 1024 + h * 128;
    float s0 = 0.f, s1 = 0.f;
    for (int m = 0; m < 128; m++){
      float w = wrow[m];
      s0 = fmaf(w, as1[h * 128 + m], s0);
      s1 = fmaf(w, ad1[h * 128 + m], s1);
    }
    us[id] = s0; ud[id] = s1;
  }
}

// one node per thread; fused global-max (wave reduce + atomicMax)
__global__ __launch_bounds__(256) void k_escore1(const float* __restrict__ x,
                                                 const float* __restrict__ us,
                                                 const float* __restrict__ ud,
                                                 float* __restrict__ ssrc,
                                                 float* __restrict__ sdst,
                                                 unsigned* __restrict__ gm, int N){
  int n = blockIdx.x * 256 + threadIdx.x;
  int lane = threadIdx.x & 63;
  float es[8], ed[8];
#pragma unroll
  for (int h = 0; h < 8; h++){ es[h] = 0.f; ed[h] = 0.f; }
  if (n < N){
    const float* xp = x + (size_t)n * 66;
    for (int c2 = 0; c2 < 33; c2++){
      float2 xv = *(const float2*)&xp[c2 * 2];
      int c = c2 * 2;
#pragma unroll
      for (int h = 0; h < 8; h++){
        es[h] = fmaf(xv.x, us[c * 8 + h], fmaf(xv.y, us[(c + 1) * 8 + h], es[h]));
        ed[h] = fmaf(xv.x, ud[c * 8 + h], fmaf(xv.y, ud[(c + 1) * 8 + h], ed[h]));
      }
    }
    *(float4*)&ssrc[(size_t)n * 8]     = (float4){es[0], es[1], es[2], es[3]};
    *(float4*)&ssrc[(size_t)n * 8 + 4] = (float4){es[4], es[5], es[6], es[7]};
    *(float4*)&sdst[(size_t)n * 8]     = (float4){ed[0], ed[1], ed[2], ed[3]};
    *(float4*)&sdst[(size_t)n * 8 + 4] = (float4){ed[4], ed[5], ed[6], ed[7]};
  }
  float me = -1e30f, md = -1e30f;
  if (n < N){
#pragma unroll
    for (int h = 0; h < 8; h++){ me = fmaxf(me, es[h]); md = fmaxf(md, ed[h]); }
  }
  me = wave_max(me); md = wave_max(md);
  if (lane == 0){ atomicMax(&gm[0], f2ord(me)); atomicMax(&gm[1], f2ord(md)); }
}

// one node per thread: single gather pass; unnormalized w -> alp, zinv per (node,head)
__global__ __launch_bounds__(256) void k_alpha1(const int* __restrict__ offs,
                                                const int* __restrict__ csr,
                                                const float* __restrict__ ssrc,
                                                const float* __restrict__ sdst,
                                                const unsigned* __restrict__ gm,
                                                float* __restrict__ alp,
                                                float* __restrict__ zinv, int N){
  int n = blockIdx.x * 256 + threadIdx.x;
  if (n >= N) return;
  float M = lrelu(ord2f(gm[0]) + ord2f(gm[1]));
  float4 sd0 = *(const float4*)&sdst[(size_t)n * 8];
  float4 sd1 = *(const float4*)&sdst[(size_t)n * 8 + 4];
  float z[8];
#pragma unroll
  for (int h = 0; h < 8; h++) z[h] = 0.f;
  int o0 = offs[n], o1 = offs[n + 1];
  for (int j = o0; j < o1; j++){
    int s = csr[j];
    float4 a0 = *(const float4*)&ssrc[(size_t)s * 8];
    float4 a1 = *(const float4*)&ssrc[(size_t)s * 8 + 4];
    float4 w0, w1;
    w0.x = __expf(lrelu(a0.x + sd0.x) - M);
    w0.y = __expf(lrelu(a0.y + sd0.y) - M);
    w0.z = __expf(lrelu(a0.z + sd0.z) - M);
    w0.w = __expf(lrelu(a0.w + sd0.w) - M);
    w1.x = __expf(lrelu(a1.x + sd1.x) - M);
    w1.y = __expf(lrelu(a1.y + sd1.y) - M);
    w1.z = __expf(lrelu(a1.z + sd1.z) - M);
    w1.w = __expf(lrelu(a1.w + sd1.w) - M);
    z[0] += w0.x; z[1] += w0.y; z[2] += w0.z; z[3] += w0.w;
    z[4] += w1.x; z[5] += w1.y; z[6] += w1.z; z[7] += w1.w;
    *(float4*)&alp[(size_t)j * 8]     = w0;
    *(float4*)&alp[(size_t)j * 8 + 4] = w1;
  }
  float4 zi0, zi1;
  zi0.x = 1.f / (z[0] + 1e-16f); zi0.y = 1.f / (z[1] + 1e-16f);
  zi0.z = 1.f / (z[2] + 1e-16f); zi0.w = 1.f / (z[3] + 1e-16f);
  zi1.x = 1.f / (z[4] + 1e-16f); zi1.y = 1.f / (z[5] + 1e-16f);
  zi1.z = 1.f / (z[6] + 1e-16f); zi1.w = 1.f / (z[7] + 1e-16f);
  *(float4*)&zinv[(size_t)n * 8]     = zi0;
  *(float4*)&zinv[(size_t)n * 8 + 4] = zi1;
}

// aggregate x; HEAD-MAJOR out: Xag[h][n][96] bf16, K padded to 96
__global__ __launch_bounds__(256) void k_agg1(const float* __restrict__ x,
                                              const int* __restrict__ offs,
                                              const int* __restrict__ csr,
                                              const float* __restrict__ alp,
                                              const float* __restrict__ zinv,
                                              __hip_bfloat16* __restrict__ Xag, int N){
  __shared__ float a_s[4][64][8];
  int tid = threadIdx.x, lane = tid & 63, wid = tid >> 6;
  int n = blockIdx.x * 4 + wid;
  if (n >= N) return;
  int o0 = offs[n], o1 = offs[n + 1];
  float acc[8], acc2[8];
#pragma unroll
  for (int h = 0; h < 8; h++){ acc[h] = 0.f; acc2[h] = 0.f; }
  int c1 = 64 + lane;

  for (int cb = o0; cb < o1; cb += 64){
    int cnt = min(64, o1 - cb);
    int sreg = (lane < cnt) ? csr[cb + lane] : 0;
    if (lane < cnt){
      const float4* ap = (const float4*)(alp + (size_t)(cb + lane) * 8);
      *(float4*)&a_s[wid][lane][0] = ap[0];
      *(float4*)&a_s[wid][lane][4] = ap[1];
    }
    for (int jj = 0; jj < cnt; jj++){
      int s = __shfl(sreg, jj, 64);
      float xv = x[(size_t)s * 66 + lane];
      float xv2 = (lane < 2) ? x[(size_t)s * 66 + c1] : 0.f;
      float4 a0 = *(const float4*)&a_s[wid][jj][0];
      float4 a1 = *(const float4*)&a_s[wid][jj][4];
      acc[0] = fmaf(a0.x, xv, acc[0]); acc[1] = fmaf(a0.y, xv, acc[1]);
      acc[2] = fmaf(a0.z, xv, acc[2]); acc[3] = fmaf(a0.w, xv, acc[3]);
      acc[4] = fmaf(a1.x, xv, acc[4]); acc[5] = fmaf(a1.y, xv, acc[5]);
      acc[6] = fmaf(a1.z, xv, acc[6]); acc[7] = fmaf(a1.w, xv, acc[7]);
      if (lane < 2){
        acc2[0] = fmaf(a0.x, xv2, acc2[0]); acc2[1] = fmaf(a0.y, xv2, acc2[1]);
        acc2[2] = fmaf(a0.z, xv2, acc2[2]); acc2[3] = fmaf(a0.w, xv2, acc2[3]);
        acc2[4] = fmaf(a1.x, xv2, acc2[4]); acc2[5] = fmaf(a1.y, xv2, acc2[5]);
        acc2[6] = fmaf(a1.z, xv2, acc2[6]); acc2[7] = fmaf(a1.w, xv2, acc2[7]);
      }
    }
  }

  float zi[8];
#pragma unroll
  for (int h = 0; h < 8; h++) zi[h] = zinv[(size_t)n * 8 + h];

  size_t slab = (size_t)N * 96;
#pragma unroll
  for (int h = 0; h < 8; h++)
    Xag[(size_t)h * slab + (size_t)n * 96 + lane] = __float2bfloat16(acc[h] * zi[h]);
  if (lane < 32){
    __hip_bfloat16 zero = __float2bfloat16(0.f);
#pragma unroll
    for (int h = 0; h < 8; h++)
      Xag[(size_t)h * slab + (size_t)n * 96 + 64 + lane] =
          (lane < 2) ? __float2bfloat16(acc2[h] * zi[h]) : zero;
  }
}

// W1 repack: W1rep[h][col][k] bf16, k in [0,96) zero-padded past 66
__global__ __launch_bounds__(256) void k_w1rep(const float* __restrict__ W1,
                                               __hip_bfloat16* __restrict__ W1rep){
  int id = blockIdx.x * 256 + threadIdx.x;
  if (id >= 8 * 128 * 96) return;
  int k = id % 96;
  int rc = id / 96;
  int col = rc & 127, h = rc >> 7;
  float v = (k < 66) ? W1[(size_t)k * 1024 + h * 128 + col] : 0.f;
  W1rep[id] = __float2bfloat16(v);
}

// layer-1 projection: barrier-free MFMA (head-major Xag) + LDS-transposed epilogue
__global__ __launch_bounds__(256) void k_gemm1_mfma(const __hip_bfloat16* __restrict__ Xag,
                                                    const __hip_bfloat16* __restrict__ W1rep,
                                                    const float* __restrict__ b1,
                                                    __hip_bfloat16* __restrict__ B, int N){
  __shared__ short ob[128 * 136];
  int tid = threadIdx.x, lane = tid & 63, w = tid >> 6;
  int r0 = blockIdx.x * 128;
  int h  = blockIdx.y;
  int wm = (w >> 1) * 64;
  int wn = (w & 1) * 64;
  int n15 = lane & 15, q = lane >> 4;
  f32x4 acc[4][4];
#pragma unroll
  for (int mi = 0; mi < 4; mi++)
#pragma unroll
    for (int ni = 0; ni < 4; ni++) acc[mi][ni] = (f32x4){0.f, 0.f, 0.f, 0.f};

  const short* Xh = (const short*)Xag + (size_t)h * N * 96;
  const short* Wg = (const short*)W1rep;

  int nodes[4];
#pragma unroll
  for (int t = 0; t < 4; t++){
    int nd = r0 + wn + t * 16 + n15;
    nodes[t] = (nd < N) ? nd : (N - 1);
  }

#pragma unroll
  for (int ks = 0; ks < 3; ks++){
    int k0 = ks * 32 + q * 8;
    short8 wf[4], xf[4];
#pragma unroll
    for (int t = 0; t < 4; t++){
      wf[t] = *(const short8*)&Wg[((size_t)h * 128 + wm + t * 16 + n15) * 96 + k0];
      xf[t] = *(const short8*)&Xh[(size_t)nodes[t] * 96 + k0];
    }
#pragma unroll
    for (int mi = 0; mi < 4; mi++)
#pragma unroll
      for (int ni = 0; ni < 4; ni++)
        acc[mi][ni] = __builtin_amdgcn_mfma_f32_16x16x32_bf16(wf[mi], xf[ni], acc[mi][ni], 0, 0, 0);
  }

#pragma unroll
  for (int mi = 0; mi < 4; mi++){
    int c0 = wm + mi * 16 + q * 4;
    float4 bb = *(const float4*)&b1[h * 128 + c0];
#pragma unroll
    for (int ni = 0; ni < 4; ni++){
      int nrow = wn + ni * 16 + n15;
      ushort4v o;
      o.x = f2bf(eluf(acc[mi][ni][0] + bb.x));
      o.y = f2bf(eluf(acc[mi][ni][1] + bb.y));
      o.z = f2bf(eluf(acc[mi][ni][2] + bb.z));
      o.w = f2bf(eluf(acc[mi][ni][3] + bb.w));
      *(ushort4v*)&ob[nrow * 136 + c0] = o;
    }
  }
  __syncthreads();

#pragma unroll
  for (int p = 0; p < 8; p++){
    int c = p * 256 + tid;
    int row = c >> 4, ch = c & 15;
    int node = r0 + row;
    if (node < N){
      short8 v = *(const short8*)&ob[row * 136 + ch * 8];
      *(short8*)((unsigned short*)B + (size_t)node * 1024 + h * 128 + ch * 8) = v;
    }
  }
}

// ---------------- W2/W3 repack ----------------

__global__ __launch_bounds__(256) void k_w2t(const float* __restrict__ W2,
                                             __hip_bfloat16* __restrict__ W2T){
  int id = blockIdx.x * 256 + threadIdx.x;
  int k = id >> 7, n = id & 127;
  W2T[(size_t)n * 1024 + k] = __float2bfloat16(W2[id]);
}

// W3 [128,64] -> W3rep[col][k] bf16 (64 x 128)
__global__ __launch_bounds__(256) void k_w3rep(const float* __restrict__ W3,
                                               __hip_bfloat16* __restrict__ W3rep){
  int id = blockIdx.x * 256 + threadIdx.x;
  if (id >= 64 * 128) return;
  int k = id & 127, col = id >> 7;
  W3rep[id] = __float2bfloat16(W3[(size_t)k * 64 + col]);
}

// ---------------- layer 2 GEMM: LDS-staged, operand-swapped, bf16 out ----------------

__global__ __launch_bounds__(256) void k_gemm2_mfma(const __hip_bfloat16* __restrict__ Abf,
                                                    const __hip_bfloat16* __restrict__ W2T,
                                                    unsigned short* __restrict__ h2, int N){
  __shared__ short As[128 * 32];
  __shared__ short Ws[128 * 32];
  int tid = threadIdx.x, lane = tid & 63, w = tid >> 6;
  int r0 = blockIdx.x * 128;
  int wm = (w >> 1) * 64;
  int wn = (w & 1) * 64;
  f32x4 acc[4][4];
#pragma unroll
  for (int mi = 0; mi < 4; mi++)
#pragma unroll
    for (int ni = 0; ni < 4; ni++) acc[mi][ni] = (f32x4){0.f, 0.f, 0.f, 0.f};

  const short* Ag = (const short*)Abf;
  const short* Bg = (const short*)W2T;

  for (int kt = 0; kt < 1024; kt += 32){
    __syncthreads();
#pragma unroll
    for (int p = 0; p < 2; p++){
      int i = p * 256 + tid;
      int row = i >> 2, c = i & 3;
      int rg = r0 + row; if (rg > N - 1) rg = N - 1;
      const short* gp = Ag + (size_t)rg * 1024 + kt + c * 8;
      __builtin_amdgcn_global_load_lds((const __attribute__((address_space(1))) void*)gp,
                                       (__attribute__((address_space(3))) void*)&As[i * 8],
                                       16, 0, 0);
      const short* gq = Bg + (size_t)row * 1024 + kt + c * 8;
      __builtin_amdgcn_global_load_lds((const __attribute__((address_space(1))) void*)gq,
                                       (__attribute__((address_space(3))) void*)&Ws[i * 8],
                                       16, 0, 0);
    }
    __syncthreads();
    int ko = (lane >> 4) * 8;
    short8 wf[4], xf[4];
#pragma unroll
    for (int t = 0; t < 4; t++){
      wf[t] = *(const short8*)&Ws[(wm + t * 16 + (lane & 15)) * 32 + ko];
      xf[t] = *(const short8*)&As[(wn + t * 16 + (lane & 15)) * 32 + ko];
    }
#pragma unroll
    for (int mi = 0; mi < 4; mi++)
#pragma unroll
      for (int ni = 0; ni < 4; ni++)
        acc[mi][ni] = __builtin_amdgcn_mfma_f32_16x16x32_bf16(wf[mi], xf[ni], acc[mi][ni], 0, 0, 0);
  }

  int n15 = lane & 15, q = lane >> 4;
#pragma unroll
  for (int mi = 0; mi < 4; mi++){
    int c0 = wm + mi * 16 + q * 4;
#pragma unroll
    for (int ni = 0; ni < 4; ni++){
      int node = r0 + wn + ni * 16 + n15;
      if (node < N){
        ushort4v o;
        o.x = f2bf(acc[mi][ni][0]); o.y = f2bf(acc[mi][ni][1]);
        o.z = f2bf(acc[mi][ni][2]); o.w = f2bf(acc[mi][ni][3]);
        *(ushort4v*)&h2[(size_t)node * 128 + c0] = o;
      }
    }
  }
}

// ---------------- layer 3 GEMM: barrier-free MFMA, bf16 in/out, no activation ----------------

__global__ __launch_bounds__(256) void k_gemm3_mfma(const unsigned short* __restrict__ out2,
                                                    const __hip_bfloat16* __restrict__ W3rep,
                                                    unsigned short* __restrict__ h3, int N){
  int tid = threadIdx.x, lane = tid & 63, w = tid >> 6;
  int r0 = blockIdx.x * 256;
  int wn = w * 64;
  int n15 = lane & 15, q = lane >> 4;
  f32x4 acc[4][4];  // [mi: col tile][ni: node tile]
#pragma unroll
  for (int mi = 0; mi < 4; mi++)
#pragma unroll
    for (int ni = 0; ni < 4; ni++) acc[mi][ni] = (f32x4){0.f, 0.f, 0.f, 0.f};

  const short* Ag = (const short*)out2;
  const short* Wg = (const short*)W3rep;

  int nodes[4];
#pragma unroll
  for (int t = 0; t < 4; t++){
    int nd = r0 + wn + t * 16 + n15;
    nodes[t] = (nd < N) ? nd : (N - 1);
  }

#pragma unroll
  for (int ks = 0; ks < 4; ks++){
    int k0 = ks * 32 + q * 8;
    short8 wf[4], xf[4];
#pragma unroll
    for (int t = 0; t < 4; t++){
      wf[t] = *(const short8*)&Wg[(size_t)(t * 16 + n15) * 128 + k0];
      xf[t] = *(const short8*)&Ag[(size_t)nodes[t] * 128 + k0];
    }
#pragma unroll
    for (int mi = 0; mi < 4; mi++)
#pragma unroll
      for (int ni = 0; ni < 4; ni++)
        acc[mi][ni] = __builtin_amdgcn_mfma_f32_16x16x32_bf16(wf[mi], xf[ni], acc[mi][ni], 0, 0, 0);
  }

#pragma unroll
  for (int mi = 0; mi < 4; mi++){
    int c0 = mi * 16 + q * 4;
#pragma unroll
    for (int ni = 0; ni < 4; ni++){
      int node = r0 + wn + ni * 16 + n15;
      if (node < N){
        ushort4v o;
        o.x = f2bf(acc[mi][ni][0]); o.y = f2bf(acc[mi][ni][1]);
        o.z = f2bf(acc[mi][ni][2]); o.w = f2bf(acc[mi][ni][3]);
        *(ushort4v*)&h3[(size_t)node * 64 + c0] = o;
      }
    }
  }
}

// ---------------- attention dots (bf16 input, fused max) + aggregation ----------------

template<int C>
__global__ __launch_bounds__(256) void k_dots(const unsigned short* __restrict__ Hb,
                                              const float* __restrict__ Asrc,
                                              const float* __restrict__ Adst,
                                              float* __restrict__ Ssrc,
                                              float* __restrict__ Sdst,
                                              unsigned* __restrict__ gmo, int N){
  int n = blockIdx.x * 256 + threadIdx.x;
  int lane = threadIdx.x & 63;
  float as_ = 0.f, ad_ = 0.f;
  if (n < N){
    const unsigned short* hp = Hb + (size_t)n * C;
    for (int c8 = 0; c8 < C / 8; c8++){
      ushort8v hv = *(const ushort8v*)&hp[c8 * 8];
      int c = c8 * 8;
#pragma unroll
      for (int j = 0; j < 8; j++){
        float h = b2f(hv[j]);
        as_ = fmaf(h, Asrc[c + j], as_);
        ad_ = fmaf(h, Adst[c + j], ad_);
      }
    }
    Ssrc[n] = as_; Sdst[n] = ad_;
  } else { as_ = -1e30f; ad_ = -1e30f; }
  float ms = wave_max(as_), md = wave_max(ad_);
  if (lane == 0){ atomicMax(&gmo[0], f2ord(ms)); atomicMax(&gmo[1], f2ord(md)); }
}

// z folded in: acc unnormalized + z in same CSR-order loop, normalize at end
template<int C, bool FINAL>
__global__ __launch_bounds__(256) void k_agg(const unsigned short* __restrict__ Hb,
                                             const int* __restrict__ offs,
                                             const int* __restrict__ csr,
                                             const float* __restrict__ Ssrc,
                                             const float* __restrict__ Sdst,
                                             const unsigned* __restrict__ gm,
                                             const float* __restrict__ bias,
                                             const float* __restrict__ Wr,
                                             const float* __restrict__ br,
                                             void* __restrict__ OutP, int N){
  int wid = threadIdx.x >> 6, lane = threadIdx.x & 63;
  int n = blockIdx.x * 4 + wid;
  if (n >= N) return;
  int o0 = offs[n], o1 = offs[n + 1];
  float M = lrelu(ord2f(gm[0]) + ord2f(gm[1]));
  float sd = Sdst[n];

  constexpr int CP = C / 64;
  float acc[CP];
#pragma unroll
  for (int r = 0; r < CP; r++) acc[r] = 0.f;
  float z = 0.f;

  for (int j = o0; j < o1; j++){
    int s = csr[j];
    float w = __expf(lrelu(Ssrc[s] + sd) - M);
    z += w;
    const unsigned short* hp = Hb + (size_t)s * C;
#pragma unroll
    for (int r = 0; r < CP; r++) acc[r] = fmaf(w, b2f(hp[lane + r * 64]), acc[r]);
  }
  float iz = 1.f / (z + 1e-16f);

  if (!FINAL){
    unsigned short* Out = (unsigned short*)OutP;
#pragma unroll
    for (int r = 0; r < CP; r++){
      int c = lane + r * 64;
      Out[(size_t)n * C + c] = f2bf(eluf(acc[r] * iz + bias[c]));
    }
  } else {
    float* Out = (float*)OutP;
    float v = eluf(acc[0] * iz + bias[lane]);
    float t = wave_sum(v * Wr[lane]);
    if (lane == 0) Out[n] = 1.f / (1.f + __expf(-(t + br[0])));
  }
}

// ---------------- host launch ----------------

extern "C" void kernel_launch(void* const* d_in, const int* in_sizes, int n_in,
                              void* d_out, int out_size, void* d_ws, size_t ws_size,
                              hipStream_t stream){
  const float* x   = (const float*)d_in[0];
  const int*   ei  = (const int*)  d_in[1];
  const float* W1  = (const float*)d_in[2];
  const float* as1 = (const float*)d_in[3];
  const float* ad1 = (const float*)d_in[4];
  const float* b1  = (const float*)d_in[5];
  const float* W2  = (const float*)d_in[6];
  const float* as2 = (const float*)d_in[7];
  const float* ad2 = (const float*)d_in[8];
  const float* b2  = (const float*)d_in[9];
  const float* W3  = (const float*)d_in[10];
  const float* as3 = (const float*)d_in[11];
  const float* ad3 = (const float*)d_in[12];
  const float* b3  = (const float*)d_in[13];
  const float* Wr  = (const float*)d_in[14];
  const float* br  = (const float*)d_in[15];

  const int N  = in_sizes[0] / 66;
  const int E  = in_sizes[1] / 2;
  const int Et = E + N;
  const int NB = (N + 1023) / 1024;
  const int NT = (N + 255) / 256;

  size_t off = 0;
  auto take = [&](size_t bytes) -> void* {
    void* p = (char*)d_ws + off;
    off = (off + bytes + 255) & ~(size_t)255;
    return p;
  };
  int*   deg    = (int*)take((size_t)2 * N * 4);
  int*   cursor = deg + N;
  int*   offs   = (int*)take((size_t)(N + 1) * 4);
  int*   csr    = (int*)take((size_t)Et * 4);
  int*   bsum   = (int*)take(64 * 4);
  int*   bbase  = (int*)take(64 * 4);
  unsigned* gm  = (unsigned*)take(8 * 4);
  float* ssrc   = (float*)take((size_t)N * 8 * 4);
  float* sdst   = (float*)take((size_t)N * 8 * 4);
  float* zi     = (float*)take((size_t)N * 8 * 4);
  float* us     = (float*)take(528 * 4);
  float* ud     = (float*)take(528 * 4);
  __hip_bfloat16* W2T   = (__hip_bfloat16*)take((size_t)128 * 1024 * 2);
  __hip_bfloat16* W1rep = (__hip_bfloat16*)take((size_t)8 * 128 * 96 * 2);
  __hip_bfloat16* W3rep = (__hip_bfloat16*)take((size_t)64 * 128 * 2);
  float* alp    = (float*)take((size_t)Et * 8 * 4);
  // union: Xag [8][N][96]bf16  vs  h2 [N,128]bf16 + out2 [N,128]bf16
  size_t xag_bytes = (size_t)N * 8 * 96 * 2;
  void*  U = take(xag_bytes);
  __hip_bfloat16* Xag = (__hip_bfloat16*)U;
  unsigned short* h2   = (unsigned short*)U;
  unsigned short* out2 = (unsigned short*)((char*)U + (size_t)N * 128 * 2);
  unsigned short* h3   = h2;  // h2 dead once out2 written
  __hip_bfloat16* B = (__hip_bfloat16*)take((size_t)N * 1024 * 2);
  (void)ws_size; (void)n_in; (void)out_size;

  // CSR build + init
  k_zero_int<<<dim3((2 * N + 255) / 256), dim3(256), 0, stream>>>(deg, 2 * N);
  k_zero_int<<<dim3(1), dim3(256), 0, stream>>>((int*)gm, 8);
  k_deg<<<dim3((Et + 255) / 256), dim3(256), 0, stream>>>(ei, E, N, deg);
  k_scan_local<<<dim3(NB), dim3(256), 0, stream>>>(deg, offs, bsum, N);
  k_scan_sums<<<dim3(1), dim3(64), 0, stream>>>(bsum, bbase, offs, N, NB);
  k_scan_add<<<dim3((N + 255) / 256), dim3(256), 0, stream>>>(offs, bbase, N);
  k_scatter<<<dim3((Et + 255) / 256), dim3(256), 0, stream>>>(ei, E, N, offs, cursor, csr);

  // layer 1
  k_uvec1<<<dim3(1), dim3(256), 0, stream>>>(W1, as1, ad1, us, ud);
  k_escore1<<<dim3(NT), dim3(256), 0, stream>>>(x, us, ud, ssrc, sdst, gm, N);
  k_alpha1<<<dim3(NT), dim3(256), 0, stream>>>(offs, csr, ssrc, sdst, gm, alp, zi, N);
  k_agg1<<<dim3((N + 3) / 4), dim3(256), 0, stream>>>(x, offs, csr, alp, zi, Xag, N);
  k_w1rep<<<dim3(384), dim3(256), 0, stream>>>(W1, W1rep);
  k_gemm1_mfma<<<dim3((N + 127) / 128, 8), dim3(256), 0, stream>>>(Xag, W1rep, b1, B, N);

  // layer 2
  k_w2t<<<dim3(512), dim3(256), 0, stream>>>(W2, W2T);
  k_gemm2_mfma<<<dim3((N + 127) / 128), dim3(256), 0, stream>>>(B, W2T, h2, N);
  k_dots<128><<<dim3(NT), dim3(256), 0, stream>>>(h2, as2, ad2, ssrc, sdst, &gm[2], N);
  k_agg<128, false><<<dim3((N + 3) / 4), dim3(256), 0, stream>>>(
      h2, offs, csr, ssrc, sdst, &gm[2], b2, nullptr, nullptr, out2, N);

  // layer 3
  k_w3rep<<<dim3(32), dim3(256), 0, stream>>>(W3, W3rep);
  k_gemm3_mfma<<<dim3((N + 255) / 256), dim3(256), 0, stream>>>(out2, W3rep, h3, N);
  k_dots<64><<<dim3(NT), dim3(256), 0, stream>>>(h3, as3, ad3, ssrc, sdst, &gm[4], N);
  k_agg<64, true><<<dim3((N + 3) / 4), dim3(256), 0, stream>>>(
      h3, offs, csr, ssrc, sdst, &gm[4], b3, Wr, br, d_out, N);
}